// Round 5
// baseline (575.416 us; speedup 1.0000x reference)
//
#include <hip/hip_runtime.h>
#include <hip/hip_bf16.h>
#include <stdint.h>

#define Bsz 4
#define Ssz 1024
#define Dsz 1024
#define Hsz 16
#define Fsz 4096

typedef __hip_bfloat16 bf16;
typedef __attribute__((ext_vector_type(8))) short bf16x8;
typedef __attribute__((ext_vector_type(4))) float f32x4;

typedef __attribute__((address_space(1))) const void gvoid_t;
typedef __attribute__((address_space(3))) void svoid_t;

__device__ __forceinline__ void gload16(const bf16* g, bf16* l) {
    __builtin_amdgcn_global_load_lds((gvoid_t*)g, (svoid_t*)l, 16, 0, 0);
}

#define WAITV(n) asm volatile("s_waitcnt vmcnt(" #n ")" ::: "memory")
#define CFENCE asm volatile("" ::: "memory")

// XCD-aware swizzle (kept from R11: measured neutral, harmless).
__device__ __forceinline__ void xcd_tiles(int p, int nT, int& n0, int& m0) {
    const int W8 = nT >> 3;
    const int n = (p & 7) * W8 + ((p >> 3) % W8);
    const int m = p / (8 * W8);
    n0 = n << 7;
    m0 = m << 7;
}

// ---------------------------------------------------------------------------
// Merged prep: blocks [0,4096) transpose+split the four D x D weights;
// blocks [4096,8192) split x into hi/lo planes (first 3 also copy qkv bias).
// ---------------------------------------------------------------------------
__global__ __launch_bounds__(256) void prep_k(const float* __restrict__ x,
                                              const float* __restrict__ Wq,
                                              const float* __restrict__ Wk,
                                              const float* __restrict__ Wv,
                                              const float* __restrict__ Wo,
                                              bf16* __restrict__ xhi,
                                              bf16* __restrict__ xlo,
                                              bf16* __restrict__ qkv_hi,
                                              bf16* __restrict__ qkv_lo,
                                              bf16* __restrict__ wo_hi,
                                              bf16* __restrict__ wo_lo,
                                              const float* __restrict__ bq,
                                              const float* __restrict__ bk,
                                              const float* __restrict__ bv,
                                              float* __restrict__ bqkv) {
    const int id = blockIdx.x;
    const int t = threadIdx.x;
    if (id < 4096) {
        __shared__ float tile[32][33];
        const int z = id >> 10, rem = id & 1023;
        const int bx = (rem & 31) * 32, by = (rem >> 5) * 32;
        const float* in = (z == 0) ? Wq : (z == 1) ? Wk : (z == 2) ? Wv : Wo;
        const size_t WP = (size_t)Dsz * Dsz;
        bf16* hiT = (z < 3) ? qkv_hi + (size_t)z * WP : wo_hi;
        bf16* loT = (z < 3) ? qkv_lo + (size_t)z * WP : wo_lo;
        const int tx = t & 31, ty = t >> 5;
        #pragma unroll
        for (int i = 0; i < 32; i += 8)
            tile[ty + i][tx] = in[(size_t)(by + ty + i) * Dsz + bx + tx];
        __syncthreads();
        #pragma unroll
        for (int i = 0; i < 32; i += 8) {
            const float v = tile[tx][ty + i];
            const bf16 h = __float2bfloat16(v);
            const size_t o = (size_t)(bx + ty + i) * Dsz + by + tx;
            hiT[o] = h;
            loT[o] = __float2bfloat16(v - __bfloat162float(h));
        }
    } else {
        const int sb = id - 4096;
        const int i = (sb * 256 + t) * 4;
        const float4 v = *(const float4*)(x + i);
        float vv[4] = {v.x, v.y, v.z, v.w};
        #pragma unroll
        for (int u = 0; u < 4; ++u) {
            const bf16 h = __float2bfloat16(vv[u]);
            xhi[i + u] = h;
            xlo[i + u] = __float2bfloat16(vv[u] - __bfloat162float(h));
        }
        if (sb < 3) {
            const float* bsrc = (sb == 0) ? bq : (sb == 1) ? bk : bv;
            const int j = t * 4;
            *(float4*)(bqkv + sb * 1024 + j) = *(const float4*)(bsrc + j);
        }
    }
}

// ---------------------------------------------------------------------------
// Pipelined hi/lo GEMM (T3+T4+T5, verified R2 on FF1): 2-deep LDS ring
// (64 KiB), raw s_barrier (no vmcnt(0) drain), counted s_waitcnt vmcnt(8)
// in steady state, setprio(1) around the 48-MFMA cluster.  Split-K over
// gridDim.z.  Numerics identical to the old gemm3_bt.
// ---------------------------------------------------------------------------
__global__ __launch_bounds__(256) void gemm3_pipe(const bf16* __restrict__ Ah,
                                                  const bf16* __restrict__ Al,
                                                  const bf16* __restrict__ Bh,
                                                  const bf16* __restrict__ Bl,
                                                  const float* __restrict__ bias,
                                                  float* __restrict__ Cf,
                                                  int M, int N, int K) {
    __shared__ alignas(16) bf16 ring[2][4][128 * 32];   // 64 KiB
    const int t = threadIdx.x;
    const int lane = t & 63, wv = t >> 6;
    const int mw = wv >> 1, nw = wv & 1;
    int n0, m0;
    xcd_tiles(blockIdx.x, N >> 7, n0, m0);
    const int z = blockIdx.z, nz = gridDim.z;
    const int Ks = K / nz, koff = z * Ks;
    const int r16 = lane & 15, q8 = (lane >> 4) * 8;
    const int arow = t >> 2, acol = (t & 3) * 8;

    const bf16* gAh = Ah + (size_t)(m0 + arow) * K + koff + acol;
    const bf16* gAl = Al + (size_t)(m0 + arow) * K + koff + acol;
    const bf16* gBh = Bh + (size_t)(n0 + arow) * K + koff + acol;
    const bf16* gBl = Bl + (size_t)(n0 + arow) * K + koff + acol;
    const size_t rK64 = (size_t)64 * K;
    const int wbase = wv * 512;

    f32x4 acc[4][4] = {};
    const int NT = Ks >> 5;

#define STAGE(kt, bi) do { \
    const int _o = (kt) << 5; \
    bf16* _l = &ring[bi][0][0]; \
    gload16(gAh + _o, _l + wbase);          gload16(gAh + _o + rK64, _l + wbase + 2048); \
    gload16(gAl + _o, _l + 4096 + wbase);   gload16(gAl + _o + rK64, _l + 4096 + wbase + 2048); \
    gload16(gBh + _o, _l + 8192 + wbase);   gload16(gBh + _o + rK64, _l + 8192 + wbase + 2048); \
    gload16(gBl + _o, _l + 12288 + wbase);  gload16(gBl + _o + rK64, _l + 12288 + wbase + 2048); \
} while (0)

#define COMPT(bi) do { \
    CFENCE; __builtin_amdgcn_s_barrier(); CFENCE; \
    const bf16* Lb = &ring[bi][0][0]; \
    bf16x8 ah[4], al[4], bh[4], bl[4]; \
    _Pragma("unroll") \
    for (int rt = 0; rt < 4; ++rt) { \
        const int ro = (64 * mw + 16 * rt + r16) * 32 + q8; \
        ah[rt] = *(const bf16x8*)(Lb + ro); \
        al[rt] = *(const bf16x8*)(Lb + 4096 + ro); \
    } \
    _Pragma("unroll") \
    for (int ct = 0; ct < 4; ++ct) { \
        const int co = (64 * nw + 16 * ct + r16) * 32 + q8; \
        bh[ct] = *(const bf16x8*)(Lb + 8192 + co); \
        bl[ct] = *(const bf16x8*)(Lb + 12288 + co); \
    } \
    asm volatile("s_waitcnt lgkmcnt(0)" ::: "memory"); \
    __builtin_amdgcn_sched_barrier(0); \
    __builtin_amdgcn_s_setprio(1); \
    _Pragma("unroll") \
    for (int rt = 0; rt < 4; ++rt) \
        _Pragma("unroll") \
        for (int ct = 0; ct < 4; ++ct) { \
            acc[rt][ct] = __builtin_amdgcn_mfma_f32_16x16x32_bf16(ah[rt], bh[ct], acc[rt][ct], 0, 0, 0); \
            acc[rt][ct] = __builtin_amdgcn_mfma_f32_16x16x32_bf16(ah[rt], bl[ct], acc[rt][ct], 0, 0, 0); \
            acc[rt][ct] = __builtin_amdgcn_mfma_f32_16x16x32_bf16(al[rt], bh[ct], acc[rt][ct], 0, 0, 0); \
        } \
    __builtin_amdgcn_s_setprio(0); \
    CFENCE; __builtin_amdgcn_s_barrier(); CFENCE; \
} while (0)

    STAGE(0, 0);
    int kt = 0;
    for (; kt < NT - 1; ++kt) {
        STAGE(kt + 1, (kt + 1) & 1);
        WAITV(8);                       // drain only tile kt's 8 loads
        COMPT(kt & 1);
    }
    WAITV(0);
    COMPT(kt & 1);

#undef STAGE
#undef COMPT

    float* Cz = Cf + (size_t)z * M * N;
    const int rowi = (lane >> 4) * 4;
    const int coli = lane & 15;
    #pragma unroll
    for (int ct = 0; ct < 4; ++ct) {
        const int col = n0 + 64 * nw + 16 * ct + coli;
        const float bvv = (z == 0) ? bias[col] : 0.f;
        #pragma unroll
        for (int rt = 0; rt < 4; ++rt) {
            const int rowb = m0 + 64 * mw + 16 * rt + rowi;
            #pragma unroll
            for (int r = 0; r < 4; ++r)
                Cz[(size_t)(rowb + r) * N + col] = acc[rt][ct][r] + bvv;
        }
    }
}

// ---------------------------------------------------------------------------
// QKV GEMM (N=3072).  R5: the 768-block grid was tail-bound at 2 blocks/CU
// (768 = 1.5 x 512 resident -> 2 rounds).  Ring shrunk to 48 KiB (3 planes:
// Ah, Al, Bh) -> 3 blocks/CU -> 768 resident -> exactly ONE round.  The Bl
// (weight-lo) fragments are read straight from global (L2-hot) into regs
// each K-step; steady-state wait = vmcnt(6) (stage kt's 6 + blr kt's 4
// drained, stage kt+1's 6 in flight).  MFMA order unchanged -> numerics
// identical.  Epilogue = R3's scalar-store version (92-VGPR class).
// ---------------------------------------------------------------------------
__global__ __launch_bounds__(256) void gemm3_qkv(const bf16* __restrict__ Ah,
                                                 const bf16* __restrict__ Al,
                                                 const bf16* __restrict__ Bh,
                                                 const bf16* __restrict__ Bl,
                                                 const float* __restrict__ bias,
                                                 bf16* __restrict__ qhi, bf16* __restrict__ qlo,
                                                 bf16* __restrict__ khi, bf16* __restrict__ klo,
                                                 bf16* __restrict__ vthi, bf16* __restrict__ vtlo) {
    const int K = Dsz;
    __shared__ alignas(16) bf16 ring[2][3][128 * 32];   // 48 KiB -> 3 blocks/CU
    const int t = threadIdx.x;
    const int lane = t & 63, wv = t >> 6;
    const int mw = wv >> 1, nw = wv & 1;
    int n0, m0;
    xcd_tiles(blockIdx.x, 3072 >> 7, n0, m0);
    const int r16 = lane & 15, q8 = (lane >> 4) * 8;
    const int arow = t >> 2, acol = (t & 3) * 8;

    const bf16* gAh = Ah + (size_t)(m0 + arow) * K + acol;
    const bf16* gAl = Al + (size_t)(m0 + arow) * K + acol;
    const bf16* gBh = Bh + (size_t)(n0 + arow) * K + acol;
    const size_t rK64 = (size_t)64 * K;
    const int wbase = wv * 512;
    // per-wave Bl fragment row pointers (lo weight plane stays in global/L2)
    const bf16* gBl0 = Bl + (size_t)(n0 + 64 * nw +  0 + r16) * K + q8;
    const bf16* gBl1 = Bl + (size_t)(n0 + 64 * nw + 16 + r16) * K + q8;
    const bf16* gBl2 = Bl + (size_t)(n0 + 64 * nw + 32 + r16) * K + q8;
    const bf16* gBl3 = Bl + (size_t)(n0 + 64 * nw + 48 + r16) * K + q8;

    f32x4 acc[4][4] = {};
    bf16x8 blr[4];
    const int NT = K >> 5;                              // 32

#define STAGE(kt, bi) do { \
    const int _o = (kt) << 5; \
    bf16* _l = &ring[bi][0][0]; \
    gload16(gAh + _o, _l + wbase);          gload16(gAh + _o + rK64, _l + wbase + 2048); \
    gload16(gAl + _o, _l + 4096 + wbase);   gload16(gAl + _o + rK64, _l + 4096 + wbase + 2048); \
    gload16(gBh + _o, _l + 8192 + wbase);   gload16(gBh + _o + rK64, _l + 8192 + wbase + 2048); \
} while (0)

#define BLOAD(kt) do { \
    const int _o = (kt) << 5; \
    blr[0] = *(const bf16x8*)(gBl0 + _o); \
    blr[1] = *(const bf16x8*)(gBl1 + _o); \
    blr[2] = *(const bf16x8*)(gBl2 + _o); \
    blr[3] = *(const bf16x8*)(gBl3 + _o); \
} while (0)

#define COMPT(bi) do { \
    CFENCE; __builtin_amdgcn_s_barrier(); CFENCE; \
    const bf16* Lb = &ring[bi][0][0]; \
    bf16x8 ah[4], al[4], bh[4]; \
    _Pragma("unroll") \
    for (int rt = 0; rt < 4; ++rt) { \
        const int ro = (64 * mw + 16 * rt + r16) * 32 + q8; \
        ah[rt] = *(const bf16x8*)(Lb + ro); \
        al[rt] = *(const bf16x8*)(Lb + 4096 + ro); \
    } \
    _Pragma("unroll") \
    for (int ct = 0; ct < 4; ++ct) { \
        const int co = (64 * nw + 16 * ct + r16) * 32 + q8; \
        bh[ct] = *(const bf16x8*)(Lb + 8192 + co); \
    } \
    asm volatile("s_waitcnt lgkmcnt(0)" ::: "memory"); \
    __builtin_amdgcn_sched_barrier(0); \
    __builtin_amdgcn_s_setprio(1); \
    _Pragma("unroll") \
    for (int rt = 0; rt < 4; ++rt) \
        _Pragma("unroll") \
        for (int ct = 0; ct < 4; ++ct) { \
            acc[rt][ct] = __builtin_amdgcn_mfma_f32_16x16x32_bf16(ah[rt], bh[ct], acc[rt][ct], 0, 0, 0); \
            acc[rt][ct] = __builtin_amdgcn_mfma_f32_16x16x32_bf16(ah[rt], blr[ct], acc[rt][ct], 0, 0, 0); \
            acc[rt][ct] = __builtin_amdgcn_mfma_f32_16x16x32_bf16(al[rt], bh[ct], acc[rt][ct], 0, 0, 0); \
        } \
    __builtin_amdgcn_s_setprio(0); \
    CFENCE; __builtin_amdgcn_s_barrier(); CFENCE; \
} while (0)

    STAGE(0, 0);
    int kt = 0;
    for (; kt < NT - 1; ++kt) {
        BLOAD(kt);
        STAGE(kt + 1, (kt + 1) & 1);
        WAITV(6);                   // stage(kt) 6 + blr(kt) 4 drained
        COMPT(kt & 1);
    }
    BLOAD(kt);
    WAITV(0);
    COMPT(kt & 1);

#undef STAGE
#undef BLOAD
#undef COMPT

    const int rowi = (lane >> 4) * 4;
    const int coli = lane & 15;
    if (n0 < 2048) {                 // ---- q or k: scalar hi/lo stores ----
        const float scale = (n0 < 1024) ? 0.125f : 1.0f;
        bf16* hip_ = (n0 < 1024) ? qhi : khi;
        bf16* lop_ = (n0 < 1024) ? qlo : klo;
        const int cbase = (n0 < 1024) ? n0 : (n0 - 1024);
        #pragma unroll
        for (int ct = 0; ct < 4; ++ct) {
            const int col = cbase + 64 * nw + 16 * ct + coli;
            const float bv = bias[n0 + 64 * nw + 16 * ct + coli];
            #pragma unroll
            for (int rt = 0; rt < 4; ++rt) {
                const int rowb = m0 + 64 * mw + 16 * rt + rowi;
                #pragma unroll
                for (int r = 0; r < 4; ++r) {
                    const float val = (acc[rt][ct][r] + bv) * scale;
                    const bf16 h = __float2bfloat16(val);
                    const size_t off = (size_t)(rowb + r) * Dsz + col;
                    hip_[off] = h;
                    lop_[off] = __float2bfloat16(val - __bfloat162float(h));
                }
            }
        }
    } else {                          // ---- v: transposed uint2 stores ----
        #pragma unroll
        for (int ct = 0; ct < 4; ++ct) {
            const int col = n0 + 64 * nw + 16 * ct + coli;
            const float bv = bias[col];
            const int c2 = col - 2048;          // (h*64 + d)
            #pragma unroll
            for (int rt = 0; rt < 4; ++rt) {
                const int rowb = m0 + 64 * mw + 16 * rt + rowi;
                const int b = rowb >> 10, s = rowb & 1023;
                bf16 hv[4], lv[4];
                #pragma unroll
                for (int r = 0; r < 4; ++r) {
                    const float val = acc[rt][ct][r] + bv;
                    hv[r] = __float2bfloat16(val);
                    lv[r] = __float2bfloat16(val - __bfloat162float(hv[r]));
                }
                const size_t vo = (size_t)b * (16 * 64 * 1024) + (size_t)c2 * 1024 + s;
                *(uint2*)&vthi[vo] = *(const uint2*)hv;
                *(uint2*)&vtlo[vo] = *(const uint2*)lv;
            }
        }
    }
}

// ---------------------------------------------------------------------------
// Single-pass GEMM, pipelined (2-deep ring, 32 KiB, vmcnt(4) steady),
// split-K over gridDim.z (bf16-exact A).
// ---------------------------------------------------------------------------
__global__ __launch_bounds__(256) void gemm1_pipe(const bf16* __restrict__ A,
                                                  const bf16* __restrict__ Bt,
                                                  const float* __restrict__ bias,
                                                  float* __restrict__ Cf,
                                                  int M, int N, int K) {
    __shared__ alignas(16) bf16 ring[2][2][128 * 32];   // 32 KiB
    const int t = threadIdx.x;
    const int lane = t & 63, wv = t >> 6;
    const int mw = wv >> 1, nw = wv & 1;
    int n0, m0;
    xcd_tiles(blockIdx.x, N >> 7, n0, m0);
    const int z = blockIdx.z, nz = gridDim.z;
    const int Ks = K / nz, koff = z * Ks;
    const int r16 = lane & 15, q8 = (lane >> 4) * 8;
    const int arow = t >> 2, acol = (t & 3) * 8;

    const bf16* gA = A + (size_t)(m0 + arow) * K + koff + acol;
    const bf16* gB = Bt + (size_t)(n0 + arow) * K + koff + acol;
    const size_t rK64 = (size_t)64 * K;
    const int wbase = wv * 512;

    f32x4 acc[4][4] = {};
    const int NT = Ks >> 5;

#define STAGE(kt, bi) do { \
    const int _o = (kt) << 5; \
    bf16* _l = &ring[bi][0][0]; \
    gload16(gA + _o, _l + wbase);          gload16(gA + _o + rK64, _l + wbase + 2048); \
    gload16(gB + _o, _l + 4096 + wbase);   gload16(gB + _o + rK64, _l + 4096 + wbase + 2048); \
} while (0)

#define COMPT(bi) do { \
    CFENCE; __builtin_amdgcn_s_barrier(); CFENCE; \
    const bf16* Lb = &ring[bi][0][0]; \
    bf16x8 af[4], bf_[4]; \
    _Pragma("unroll") \
    for (int rt = 0; rt < 4; ++rt) \
        af[rt] = *(const bf16x8*)(Lb + (64 * mw + 16 * rt + r16) * 32 + q8); \
    _Pragma("unroll") \
    for (int ct = 0; ct < 4; ++ct) \
        bf_[ct] = *(const bf16x8*)(Lb + 4096 + (64 * nw + 16 * ct + r16) * 32 + q8); \
    asm volatile("s_waitcnt lgkmcnt(0)" ::: "memory"); \
    __builtin_amdgcn_sched_barrier(0); \
    __builtin_amdgcn_s_setprio(1); \
    _Pragma("unroll") \
    for (int rt = 0; rt < 4; ++rt) \
        _Pragma("unroll") \
        for (int ct = 0; ct < 4; ++ct) \
            acc[rt][ct] = __builtin_amdgcn_mfma_f32_16x16x32_bf16( \
                af[rt], bf_[ct], acc[rt][ct], 0, 0, 0); \
    __builtin_amdgcn_s_setprio(0); \
    CFENCE; __builtin_amdgcn_s_barrier(); CFENCE; \
} while (0)

    STAGE(0, 0);
    int kt = 0;
    for (; kt < NT - 1; ++kt) {
        STAGE(kt + 1, (kt + 1) & 1);
        WAITV(4);
        COMPT(kt & 1);
    }
    WAITV(0);
    COMPT(kt & 1);

#undef STAGE
#undef COMPT

    float* Cz = Cf + (size_t)z * M * N;
    const int rowi = (lane >> 4) * 4;
    const int coli = lane & 15;
    #pragma unroll
    for (int ct = 0; ct < 4; ++ct) {
        const int col = n0 + 64 * nw + 16 * ct + coli;
        const float bv = (z == 0) ? bias[col] : 0.f;
        #pragma unroll
        for (int rt = 0; rt < 4; ++rt) {
            const int rowb = m0 + 64 * mw + 16 * rt + rowi;
            #pragma unroll
            for (int r = 0; r < 4; ++r)
                Cz[(size_t)(rowb + r) * N + col] = acc[rt][ct][r] + bv;
        }
    }
}

// ---------------------------------------------------------------------------
// MFMA causal flash attention v4 — barrier-free + mirror-paired strips.
// ---------------------------------------------------------------------------
__global__ __launch_bounds__(512) void attn_mfma_k(const bf16* __restrict__ qhp,
                                                   const bf16* __restrict__ qlp,
                                                   const bf16* __restrict__ khp,
                                                   const bf16* __restrict__ klp,
                                                   const bf16* __restrict__ vhp,
                                                   const bf16* __restrict__ vlp,
                                                   bf16* __restrict__ ohi,
                                                   bf16* __restrict__ olo) {
    __shared__ alignas(16) float Pf[256 * 68];              // 69632 B

    const int bh = blockIdx.x;
    const int b = bh >> 4, h = bh & 15;
    const int pr = blockIdx.y;                              // 0..3
    const int t = threadIdx.x, w = t >> 6, lane = t & 63;
    const int r16 = lane & 15, quad = lane >> 4;
    const int strip = (w < 4) ? pr : 7 - pr;
    const int qw = strip * 128 + 32 * (w & 3);              // wave's first query

    bf16x8 aQh[2][2], aQl[2][2];
    #pragma unroll
    for (int mt = 0; mt < 2; ++mt) {
        const size_t qb = (size_t)(b * Ssz + qw + 16 * mt + r16) * Dsz + h * 64 + quad * 8;
        aQh[mt][0] = *(const bf16x8*)(qhp + qb);
        aQh[mt][1] = *(const bf16x8*)(qhp + qb + 32);
        aQl[mt][0] = *(const bf16x8*)(qlp + qb);
        aQl[mt][1] = *(const bf16x8*)(qlp + qb + 32);
    }

    f32x4 aco[2][4] = {};
    float lrun[2][4] = {};
    const int ntiles = (qw + 31) / 64 + 1;

    for (int kt = 0; kt < ntiles; ++kt) {
        #pragma unroll
        for (int nt = 0; nt < 4; ++nt) {
            const size_t kb = (size_t)(b * Ssz + kt * 64 + nt * 16 + r16) * Dsz + h * 64 + quad * 8;
            const bf16x8 bKh0 = *(const bf16x8*)(khp + kb);
            const bf16x8 bKh1 = *(const bf16x8*)(khp + kb + 32);
            const bf16x8 bKl0 = *(const bf16x8*)(klp + kb);
            const bf16x8 bKl1 = *(const bf16x8*)(klp + kb + 32);
            const int key = kt * 64 + nt * 16 + r16;
            #pragma unroll
            for (int mt = 0; mt < 2; ++mt) {
                f32x4 s = {};
                s = __builtin_amdgcn_mfma_f32_16x16x32_bf16(aQh[mt][0], bKh0, s, 0, 0, 0);
                s = __builtin_amdgcn_mfma_f32_16x16x32_bf16(aQh[mt][0], bKl0, s, 0, 0, 0);
                s = __builtin_amdgcn_mfma_f32_16x16x32_bf16(aQl[mt][0], bKh0, s, 0, 0, 0);
                s = __builtin_amdgcn_mfma_f32_16x16x32_bf16(aQh[mt][1], bKh1, s, 0, 0, 0);
                s = __builtin_amdgcn_mfma_f32_16x16x32_bf16(aQh[mt][1], bKl1, s, 0, 0, 0);
                s = __builtin_amdgcn_mfma_f32_16x16x32_bf16(aQl[mt][1], bKh1, s, 0, 0, 0);
                #pragma unroll
                for (int r = 0; r < 4; ++r) {
                    const int qrow = qw + 16 * mt + quad * 4 + r;
                    const float p = (key <= qrow) ? __expf(s[r]) : 0.f;
                    lrun[mt][r] += p;
                    Pf[(32 * w + 16 * mt + quad * 4 + r) * 68 + nt * 16 + r16] = p;
                }
            }
        }

        bf16x8 aPh[2][2], aPl[2][2];
        #pragma unroll
        for (int mt = 0; mt < 2; ++mt)
            #pragma unroll
            for (int ks = 0; ks < 2; ++ks) {
                const float* pr_ = &Pf[(32 * w + 16 * mt + r16) * 68 + ks * 32 + quad * 8];
                const float4 pa = *(const float4*)pr_;
                const float4 pb = *(const float4*)(pr_ + 4);
                const float pv[8] = {pa.x, pa.y, pa.z, pa.w, pb.x, pb.y, pb.z, pb.w};
                bf16 hv[8], lv[8];
                #pragma unroll
                for (int j = 0; j < 8; ++j) {
                    hv[j] = __float2bfloat16(pv[j]);
                    lv[j] = __float2bfloat16(pv[j] - __bfloat162float(hv[j]));
                }
                aPh[mt][ks] = *(const bf16x8*)hv;
                aPl[mt][ks] = *(const bf16x8*)lv;
            }

        #pragma unroll
        for (int nt = 0; nt < 4; ++nt) {
            const size_t vb = ((size_t)bh * 64 + nt * 16 + r16) * Ssz + kt * 64 + quad * 8;
            const bf16x8 bVh0 = *(const bf16x8*)(vhp + vb);
            const bf16x8 bVh1 = *(const bf16x8*)(vhp + vb + 32);
            const bf16x8 bVl0 = *(const bf16x8*)(vlp + vb);
            const bf16x8 bVl1 = *(const bf16x8*)(vlp + vb + 32);
            #pragma unroll
            for (int mt = 0; mt < 2; ++mt) {
                aco[mt][nt] = __builtin_amdgcn_mfma_f32_16x16x32_bf16(aPh[mt][0], bVh0, aco[mt][nt], 0, 0, 0);
                aco[mt][nt] = __builtin_amdgcn_mfma_f32_16x16x32_bf16(aPh[mt][0], bVl0, aco[mt][nt], 0, 0, 0);
                aco[mt][nt] = __builtin_amdgcn_mfma_f32_16x16x32_bf16(aPl[mt][0], bVh0, aco[mt][nt], 0, 0, 0);
                aco[mt][nt] = __builtin_amdgcn_mfma_f32_16x16x32_bf16(aPh[mt][1], bVh1, aco[mt][nt], 0, 0, 0);
                aco[mt][nt] = __builtin_amdgcn_mfma_f32_16x16x32_bf16(aPh[mt][1], bVl1, aco[mt][nt], 0, 0, 0);
                aco[mt][nt] = __builtin_amdgcn_mfma_f32_16x16x32_bf16(aPl[mt][1], bVh1, aco[mt][nt], 0, 0, 0);
            }
        }
    }

    #pragma unroll
    for (int mt = 0; mt < 2; ++mt)
        #pragma unroll
        for (int r = 0; r < 4; ++r) {
            float l = lrun[mt][r];
            l += __shfl_xor(l, 1); l += __shfl_xor(l, 2);
            l += __shfl_xor(l, 4); l += __shfl_xor(l, 8);
            lrun[mt][r] = l;
        }
    #pragma unroll
    for (int mt = 0; mt < 2; ++mt)
        #pragma unroll
        for (int nt = 0; nt < 4; ++nt)
            #pragma unroll
            for (int r = 0; r < 4; ++r) {
                const size_t off = (size_t)(b * Ssz + qw + 16 * mt + quad * 4 + r) * Dsz
                                   + h * 64 + nt * 16 + r16;
                const float val = aco[mt][nt][r] / lrun[mt][r];
                const bf16 hh = __float2bfloat16(val);
                ohi[off] = hh;
                olo[off] = __float2bfloat16(val - __bfloat162float(hh));
            }
}

// ---------------------------------------------------------------------------
// LIF scan (blocks [0,64), 256 thr) MERGED with W2 transpose-cast (blocks
// [64,4160)).  Cast blocks ride along the long-running scan blocks.
// ---------------------------------------------------------------------------
__global__ __launch_bounds__(256) void scan_w2_k(const float* __restrict__ ff,
                                                 const float* __restrict__ decay,
                                                 const float* __restrict__ beta,
                                                 bf16* __restrict__ spikes,
                                                 const float* __restrict__ W2,
                                                 bf16* __restrict__ W2T) {
    __shared__ float tile[32][33];
    const int id = blockIdx.x;
    const int t = threadIdx.x;
    if (id >= 64) {
        // W2 [4096][1024] -> W2T [1024][4096] (bf16 cast)
        const int rem = id - 64;
        const int bx = (rem & 31) * 32;          // col tile over Dsz
        const int by = (rem >> 5) * 32;          // row tile over Fsz
        const int tx = t & 31, ty = t >> 5;
        #pragma unroll
        for (int i = 0; i < 32; i += 8)
            tile[ty + i][tx] = W2[(size_t)(by + ty + i) * Dsz + bx + tx];
        __syncthreads();
        #pragma unroll
        for (int i = 0; i < 32; i += 8)
            W2T[(size_t)(bx + ty + i) * Fsz + by + tx] =
                __float2bfloat16(tile[tx][ty + i]);
        return;
    }
    const int idx = id * 256 + t;
    const int b = idx >> 12;
    const int f = idx & (Fsz - 1);
    const float dec = decay[f];
    const float bet = beta[f];
    const float* src = ff + (size_t)b * Ssz * Fsz + f;
    bf16* dst = spikes + (size_t)b * Ssz * Fsz + f;
    float vm = 0.f, a = 0.f;
    float buf[64];
    #pragma unroll
    for (int u = 0; u < 64; ++u) buf[u] = src[(size_t)u * Fsz];
    for (int gg = 0; gg < 16; ++gg) {
        #pragma unroll
        for (int sub = 0; sub < 4; ++sub) {
            const int g = gg * 4 + sub;
            #pragma unroll
            for (int u = 0; u < 16; ++u) {
                vm = dec * vm + buf[sub * 16 + u];
                const float uu = vm - (1.f + a);
                const float sp = (uu > 0.f) ? 1.f : 0.f;
                vm = (uu > 0.f) ? 0.f : vm;
                a = 0.9f * a + bet * sp;
                dst[(size_t)(g * 16 + u) * Fsz] = __float2bfloat16(sp);
            }
            if (g + 4 < 64) {
                #pragma unroll
                for (int u = 0; u < 16; ++u)
                    buf[sub * 16 + u] = src[(size_t)((g + 4) * 16 + u) * Fsz];
            }
        }
    }
}

// ---------------------------------------------------------------------------
// LayerNorm 1 (blocks [0,4096)) MERGED with W1 transpose-split (blocks
// [4096,8192)).  A2 arena is free at this point (Wqkv/WoT dead).
// ---------------------------------------------------------------------------
__device__ __forceinline__ float block_sum(float val, float* ls, int t) {
    #pragma unroll
    for (int mm = 32; mm >= 1; mm >>= 1) val += __shfl_xor(val, mm);
    if ((t & 63) == 0) ls[t >> 6] = val;
    __syncthreads();
    const float r = ls[0] + ls[1] + ls[2] + ls[3];
    __syncthreads();
    return r;
}

__global__ __launch_bounds__(256) void ln1_w1_k(const float* __restrict__ x,
                                                const float* __restrict__ ap0,
                                                const float* __restrict__ ap1,
                                                const float* __restrict__ g,
                                                const float* __restrict__ bb,
                                                bf16* __restrict__ h_hi,
                                                bf16* __restrict__ h_lo,
                                                const float* __restrict__ W1,
                                                bf16* __restrict__ W1Thi,
                                                bf16* __restrict__ W1Tlo) {
    __shared__ float ls[4];
    __shared__ float tile[32][33];
    const int id = blockIdx.x;
    const int t = threadIdx.x;
    if (id >= 4096) {
        // W1 [1024][4096] -> W1T hi/lo [4096][1024]
        const int rem = id - 4096;
        const int bx = (rem & 127) * 32;         // col tile over Fsz
        const int by = (rem >> 7) * 32;          // row tile over Dsz
        const int tx = t & 31, ty = t >> 5;
        #pragma unroll
        for (int i = 0; i < 32; i += 8)
            tile[ty + i][tx] = W1[(size_t)(by + ty + i) * Fsz + bx + tx];
        __syncthreads();
        #pragma unroll
        for (int i = 0; i < 32; i += 8) {
            const float v = tile[tx][ty + i];
            const bf16 h = __float2bfloat16(v);
            const size_t o = (size_t)(bx + ty + i) * Dsz + by + tx;
            W1Thi[o] = h;
            W1Tlo[o] = __float2bfloat16(v - __bfloat162float(h));
        }
        return;
    }
    const int row = id;
    const size_t base = (size_t)row * Dsz;
    float vv[4];
    #pragma unroll
    for (int i = 0; i < 4; ++i) {
        const int c = t + i * 256;
        vv[i] = x[base + c] + (ap0[base + c] + ap1[base + c]);
    }
    float s = vv[0] + vv[1] + vv[2] + vv[3];
    s = block_sum(s, ls, t);
    const float mu = s * (1.f / 1024.f);
    float qs = 0.f;
    #pragma unroll
    for (int i = 0; i < 4; ++i) { const float d = vv[i] - mu; qs += d * d; }
    qs = block_sum(qs, ls, t);
    const float rs = rsqrtf(qs * (1.f / 1024.f) + 1e-5f);
    #pragma unroll
    for (int i = 0; i < 4; ++i) {
        const int c = t + i * 256;
        const float o = (vv[i] - mu) * rs * g[c] + bb[c];
        const bf16 hi = __float2bfloat16(o);
        h_hi[base + c] = hi;
        h_lo[base + c] = __float2bfloat16(o - __bfloat162float(hi));
    }
}

__global__ __launch_bounds__(256) void ln2_k(const bf16* __restrict__ h_hi,
                                             const bf16* __restrict__ h_lo,
                                             const float* __restrict__ fo0,
                                             const float* __restrict__ fo1,
                                             const float* __restrict__ g,
                                             const float* __restrict__ bb,
                                             float* __restrict__ out) {
    __shared__ float ls[4];
    const int row = blockIdx.x;
    const int t = threadIdx.x;
    const size_t base = (size_t)row * Dsz;
    float vv[4];
    #pragma unroll
    for (int i = 0; i < 4; ++i) {
        const int c = t + i * 256;
        const float h = __bfloat162float(h_hi[base + c]) + __bfloat162float(h_lo[base + c]);
        vv[i] = h + (fo0[base + c] + fo1[base + c]);
    }
    float s = vv[0] + vv[1] + vv[2] + vv[3];
    s = block_sum(s, ls, t);
    const float mu = s * (1.f / 1024.f);
    float qs = 0.f;
    #pragma unroll
    for (int i = 0; i < 4; ++i) { const float d = vv[i] - mu; qs += d * d; }
    qs = block_sum(qs, ls, t);
    const float rs = rsqrtf(qs * (1.f / 1024.f) + 1e-5f);
    #pragma unroll
    for (int i = 0; i < 4; ++i) {
        const int c = t + i * 256;
        out[base + c] = (vv[i] - mu) * rs * g[c] + bb[c];
    }
}

// ---------------------------------------------------------------------------
extern "C" void kernel_launch(void* const* d_in, const int* in_sizes, int n_in,
                              void* d_out, int out_size, void* d_ws, size_t ws_size,
                              hipStream_t stream) {
    const float* x    = (const float*)d_in[0];
    const float* Wq   = (const float*)d_in[1];
    const float* bq   = (const float*)d_in[2];
    const float* Wk   = (const float*)d_in[3];
    const float* bk   = (const float*)d_in[4];
    const float* Wv   = (const float*)d_in[5];
    const float* bv   = (const float*)d_in[6];
    const float* Wo   = (const float*)d_in[7];
    const float* bo   = (const float*)d_in[8];
    const float* g1   = (const float*)d_in[9];
    const float* b1   = (const float*)d_in[10];
    const float* W1   = (const float*)d_in[11];
    const float* bf1  = (const float*)d_in[12];
    const float* W2   = (const float*)d_in[13];
    const float* bf2  = (const float*)d_in[14];
    const float* g2   = (const float*)d_in[15];
    const float* b2   = (const float*)d_in[16];
    const float* dec  = (const float*)d_in[17];
    const float* beta = (const float*)d_in[18];

    const size_t BSD = (size_t)Bsz * Ssz * Dsz;
    const size_t BSF = (size_t)Bsz * Ssz * Fsz;

    // ---- workspace arenas with liveness reuse ----
    char* ws = (char*)d_ws;
    char* A3 = ws;                               // 67.1 MB
    char* A1 = A3 + BSF * 4;                     // 33.6 MB
    char* A2 = A1 + BSF * 2;                     // 16.8 MB
    char* A4 = A2 + (size_t)Dsz * Fsz * 2 * 2;   // 16.8 MB
    float* bqkv = (float*)(A4 + BSD * 4);        // 12 KB

    bf16* qhi   = (bf16*)(A3);
    bf16* qlo   = (bf16*)(A3 + BSD * 2);
    bf16* khi   = (bf16*)(A3 + BSD * 4);
    bf16* klo   = (bf16*)(A3 + BSD * 6);
    float* attnp = (float*)(A3);
    float* ffb   = (float*)(A3);
    float* ffout = (float*)(A3);

    bf16* xhi    = (bf16*)(A1);
    bf16* xlo    = (bf16*)(A1 + BSD * 2);
    bf16* athi   = (bf16*)(A1);
    bf16* atlo   = (bf16*)(A1 + BSD * 2);
    bf16* spikes = (bf16*)(A1);

    const size_t WP = (size_t)Dsz * Dsz;
    bf16* Wqkv_hi = (bf16*)(A2);
    bf16* Wqkv_lo = (bf16*)(A2 + WP * 3 * 2);
    bf16* WoThi   = (bf16*)(A2 + WP * 6 * 2);
    bf16* WoTlo   = (bf16*)(A2 + WP * 7 * 2);
    bf16* W1Thi   = (bf16*)(A2);                 // written by ln1_w1 (A2 free then)
    bf16* W1Tlo   = (bf16*)(A2 + (size_t)Dsz * Fsz * 2);
    bf16* W2T     = (bf16*)(A2);                 // written by scan_w2 (W1T dead then)

    bf16* vthi  = (bf16*)(A4);                  // [B,H,DH,S]
    bf16* vtlo  = (bf16*)(A4 + BSD * 2);
    bf16* h_hi  = (bf16*)(A4);
    bf16* h_lo  = (bf16*)(A4 + BSD * 2);

    (void)ws_size; (void)in_sizes; (void)n_in; (void)out_size;

    const int MBS = Bsz * Ssz;

    // Phase A: merged prep (4 DxD weight transpose-splits + x split + bias)
    prep_k<<<8192, 256, 0, stream>>>(x, Wq, Wk, Wv, Wo, xhi, xlo,
                                     Wqkv_hi, Wqkv_lo, WoThi, WoTlo,
                                     bq, bk, bv, bqkv);

    // Phase B: fused QKV projection (48 KiB ring, 3 blocks/CU, single round)
    gemm3_qkv<<<dim3(24 * 32), 256, 0, stream>>>(
        xhi, xlo, Wqkv_hi, Wqkv_lo, bqkv, qhi, qlo, khi, klo, vthi, vtlo);

    // Phase C: barrier-free, mirror-paired MFMA attention
    attn_mfma_k<<<dim3(Bsz * Hsz, 4), 512, 0, stream>>>(
        qhi, qlo, khi, klo, vthi, vtlo, athi, atlo);

    // Phase D: output projection (split-K=2, pipelined) + LN1 (+W1T prep)
    gemm3_pipe<<<dim3(8 * 32, 1, 2), 256, 0, stream>>>(
        athi, atlo, WoThi, WoTlo, bo, attnp, MBS, Dsz, Dsz);
    ln1_w1_k<<<8192, 256, 0, stream>>>(x, attnp, attnp + (size_t)MBS * Dsz,
                                       g1, b1, h_hi, h_lo, W1, W1Thi, W1Tlo);

    // Phase E: FF1 — pipelined (2-deep ring, counted vmcnt, setprio)
    gemm3_pipe<<<dim3(32 * 32), 256, 0, stream>>>(
        h_hi, h_lo, W1Thi, W1Tlo, bf1, ffb, MBS, Fsz, Dsz);

    // Phase F: LIF scan (+W2T prep merged)
    scan_w2_k<<<64 + 4096, 256, 0, stream>>>(ffb, dec, beta, spikes, W2, W2T);

    // Phase G: FF2 (split-K=2, pipelined)
    gemm1_pipe<<<dim3(8 * 32, 1, 2), 256, 0, stream>>>(
        spikes, W2T, bf2, ffout, MBS, Dsz, Fsz);

    // Phase H: LN2 -> d_out
    ln2_k<<<MBS, 256, 0, stream>>>(h_hi, h_lo, ffout, ffout + (size_t)MBS * Dsz,
                                   g2, b2, (float*)d_out);
}

// Round 6
// 566.925 us; speedup vs baseline: 1.0150x; 1.0150x over previous
//
#include <hip/hip_runtime.h>
#include <hip/hip_bf16.h>
#include <stdint.h>

#define Bsz 4
#define Ssz 1024
#define Dsz 1024
#define Hsz 16
#define Fsz 4096

typedef __hip_bfloat16 bf16;
typedef __attribute__((ext_vector_type(8))) short bf16x8;
typedef __attribute__((ext_vector_type(4))) float f32x4;

typedef __attribute__((address_space(1))) const void gvoid_t;
typedef __attribute__((address_space(3))) void svoid_t;

__device__ __forceinline__ void gload16(const bf16* g, bf16* l) {
    __builtin_amdgcn_global_load_lds((gvoid_t*)g, (svoid_t*)l, 16, 0, 0);
}

#define WAITV(n) asm volatile("s_waitcnt vmcnt(" #n ")" ::: "memory")
#define CFENCE asm volatile("" ::: "memory")

// XCD-aware swizzle (kept from R11: measured neutral, harmless).
__device__ __forceinline__ void xcd_tiles(int p, int nT, int& n0, int& m0) {
    const int W8 = nT >> 3;
    const int n = (p & 7) * W8 + ((p >> 3) % W8);
    const int m = p / (8 * W8);
    n0 = n << 7;
    m0 = m << 7;
}

// ---------------------------------------------------------------------------
// Merged prep: blocks [0,4096) transpose+split the four D x D weights;
// blocks [4096,8192) split x into hi/lo planes (first 3 also copy qkv bias).
// ---------------------------------------------------------------------------
__global__ __launch_bounds__(256) void prep_k(const float* __restrict__ x,
                                              const float* __restrict__ Wq,
                                              const float* __restrict__ Wk,
                                              const float* __restrict__ Wv,
                                              const float* __restrict__ Wo,
                                              bf16* __restrict__ xhi,
                                              bf16* __restrict__ xlo,
                                              bf16* __restrict__ qkv_hi,
                                              bf16* __restrict__ qkv_lo,
                                              bf16* __restrict__ wo_hi,
                                              bf16* __restrict__ wo_lo,
                                              const float* __restrict__ bq,
                                              const float* __restrict__ bk,
                                              const float* __restrict__ bv,
                                              float* __restrict__ bqkv) {
    const int id = blockIdx.x;
    const int t = threadIdx.x;
    if (id < 4096) {
        __shared__ float tile[32][33];
        const int z = id >> 10, rem = id & 1023;
        const int bx = (rem & 31) * 32, by = (rem >> 5) * 32;
        const float* in = (z == 0) ? Wq : (z == 1) ? Wk : (z == 2) ? Wv : Wo;
        const size_t WP = (size_t)Dsz * Dsz;
        bf16* hiT = (z < 3) ? qkv_hi + (size_t)z * WP : wo_hi;
        bf16* loT = (z < 3) ? qkv_lo + (size_t)z * WP : wo_lo;
        const int tx = t & 31, ty = t >> 5;
        #pragma unroll
        for (int i = 0; i < 32; i += 8)
            tile[ty + i][tx] = in[(size_t)(by + ty + i) * Dsz + bx + tx];
        __syncthreads();
        #pragma unroll
        for (int i = 0; i < 32; i += 8) {
            const float v = tile[tx][ty + i];
            const bf16 h = __float2bfloat16(v);
            const size_t o = (size_t)(bx + ty + i) * Dsz + by + tx;
            hiT[o] = h;
            loT[o] = __float2bfloat16(v - __bfloat162float(h));
        }
    } else {
        const int sb = id - 4096;
        const int i = (sb * 256 + t) * 4;
        const float4 v = *(const float4*)(x + i);
        float vv[4] = {v.x, v.y, v.z, v.w};
        #pragma unroll
        for (int u = 0; u < 4; ++u) {
            const bf16 h = __float2bfloat16(vv[u]);
            xhi[i + u] = h;
            xlo[i + u] = __float2bfloat16(vv[u] - __bfloat162float(h));
        }
        if (sb < 3) {
            const float* bsrc = (sb == 0) ? bq : (sb == 1) ? bk : bv;
            const int j = t * 4;
            *(float4*)(bqkv + sb * 1024 + j) = *(const float4*)(bsrc + j);
        }
    }
}

// ---------------------------------------------------------------------------
// Pipelined hi/lo GEMM (T3+T4+T5, verified R2 on FF1): 2-deep LDS ring
// (64 KiB), raw s_barrier (no vmcnt(0) drain), counted s_waitcnt vmcnt(8)
// in steady state, setprio(1) around the 48-MFMA cluster.  Split-K over
// gridDim.z.  Numerics identical to the old gemm3_bt.
// ---------------------------------------------------------------------------
__global__ __launch_bounds__(256) void gemm3_pipe(const bf16* __restrict__ Ah,
                                                  const bf16* __restrict__ Al,
                                                  const bf16* __restrict__ Bh,
                                                  const bf16* __restrict__ Bl,
                                                  const float* __restrict__ bias,
                                                  float* __restrict__ Cf,
                                                  int M, int N, int K) {
    __shared__ alignas(16) bf16 ring[2][4][128 * 32];   // 64 KiB
    const int t = threadIdx.x;
    const int lane = t & 63, wv = t >> 6;
    const int mw = wv >> 1, nw = wv & 1;
    int n0, m0;
    xcd_tiles(blockIdx.x, N >> 7, n0, m0);
    const int z = blockIdx.z, nz = gridDim.z;
    const int Ks = K / nz, koff = z * Ks;
    const int r16 = lane & 15, q8 = (lane >> 4) * 8;
    const int arow = t >> 2, acol = (t & 3) * 8;

    const bf16* gAh = Ah + (size_t)(m0 + arow) * K + koff + acol;
    const bf16* gAl = Al + (size_t)(m0 + arow) * K + koff + acol;
    const bf16* gBh = Bh + (size_t)(n0 + arow) * K + koff + acol;
    const bf16* gBl = Bl + (size_t)(n0 + arow) * K + koff + acol;
    const size_t rK64 = (size_t)64 * K;
    const int wbase = wv * 512;

    f32x4 acc[4][4] = {};
    const int NT = Ks >> 5;

#define STAGE(kt, bi) do { \
    const int _o = (kt) << 5; \
    bf16* _l = &ring[bi][0][0]; \
    gload16(gAh + _o, _l + wbase);          gload16(gAh + _o + rK64, _l + wbase + 2048); \
    gload16(gAl + _o, _l + 4096 + wbase);   gload16(gAl + _o + rK64, _l + 4096 + wbase + 2048); \
    gload16(gBh + _o, _l + 8192 + wbase);   gload16(gBh + _o + rK64, _l + 8192 + wbase + 2048); \
    gload16(gBl + _o, _l + 12288 + wbase);  gload16(gBl + _o + rK64, _l + 12288 + wbase + 2048); \
} while (0)

#define COMPT(bi) do { \
    CFENCE; __builtin_amdgcn_s_barrier(); CFENCE; \
    const bf16* Lb = &ring[bi][0][0]; \
    bf16x8 ah[4], al[4], bh[4], bl[4]; \
    _Pragma("unroll") \
    for (int rt = 0; rt < 4; ++rt) { \
        const int ro = (64 * mw + 16 * rt + r16) * 32 + q8; \
        ah[rt] = *(const bf16x8*)(Lb + ro); \
        al[rt] = *(const bf16x8*)(Lb + 4096 + ro); \
    } \
    _Pragma("unroll") \
    for (int ct = 0; ct < 4; ++ct) { \
        const int co = (64 * nw + 16 * ct + r16) * 32 + q8; \
        bh[ct] = *(const bf16x8*)(Lb + 8192 + co); \
        bl[ct] = *(const bf16x8*)(Lb + 12288 + co); \
    } \
    asm volatile("s_waitcnt lgkmcnt(0)" ::: "memory"); \
    __builtin_amdgcn_sched_barrier(0); \
    __builtin_amdgcn_s_setprio(1); \
    _Pragma("unroll") \
    for (int rt = 0; rt < 4; ++rt) \
        _Pragma("unroll") \
        for (int ct = 0; ct < 4; ++ct) { \
            acc[rt][ct] = __builtin_amdgcn_mfma_f32_16x16x32_bf16(ah[rt], bh[ct], acc[rt][ct], 0, 0, 0); \
            acc[rt][ct] = __builtin_amdgcn_mfma_f32_16x16x32_bf16(ah[rt], bl[ct], acc[rt][ct], 0, 0, 0); \
            acc[rt][ct] = __builtin_amdgcn_mfma_f32_16x16x32_bf16(al[rt], bh[ct], acc[rt][ct], 0, 0, 0); \
        } \
    __builtin_amdgcn_s_setprio(0); \
    CFENCE; __builtin_amdgcn_s_barrier(); CFENCE; \
} while (0)

    STAGE(0, 0);
    int kt = 0;
    for (; kt < NT - 1; ++kt) {
        STAGE(kt + 1, (kt + 1) & 1);
        WAITV(8);                       // drain only tile kt's 8 loads
        COMPT(kt & 1);
    }
    WAITV(0);
    COMPT(kt & 1);

#undef STAGE
#undef COMPT

    float* Cz = Cf + (size_t)z * M * N;
    const int rowi = (lane >> 4) * 4;
    const int coli = lane & 15;
    #pragma unroll
    for (int ct = 0; ct < 4; ++ct) {
        const int col = n0 + 64 * nw + 16 * ct + coli;
        const float bvv = (z == 0) ? bias[col] : 0.f;
        #pragma unroll
        for (int rt = 0; rt < 4; ++rt) {
            const int rowb = m0 + 64 * mw + 16 * rt + rowi;
            #pragma unroll
            for (int r = 0; r < 4; ++r)
                Cz[(size_t)(rowb + r) * N + col] = acc[rt][ct][r] + bvv;
        }
    }
}

// ---------------------------------------------------------------------------
// QKV GEMM (N=3072).  R6: keep the 48 KiB ring (3 blocks/CU target, single
// round for the 768-block grid) but fix R5's regression: the per-lane Bl
// register loads were issued immediately before the wait that drained them,
// exposing L2 latency every K-step.  Now Bl(kt+1) is prefetched into a
// SECOND named register set (blrA/blrB ping-pong, statically indexed) at the
// top of iter kt, so each Bl load gets a full COMPT of MFMA work as cover.
// vmcnt: pre-loop 10 outstanding (blr0 4 + stage0 6); each iter issues 10
// and WAITV(10) drains exactly tile kt's 10.  __launch_bounds__(256,3) pins
// the 3-waves/SIMD occupancy target.  MFMA order unchanged -> numerics
// identical.
// ---------------------------------------------------------------------------
__global__ __launch_bounds__(256, 3) void gemm3_qkv(const bf16* __restrict__ Ah,
                                                    const bf16* __restrict__ Al,
                                                    const bf16* __restrict__ Bh,
                                                    const bf16* __restrict__ Bl,
                                                    const float* __restrict__ bias,
                                                    bf16* __restrict__ qhi, bf16* __restrict__ qlo,
                                                    bf16* __restrict__ khi, bf16* __restrict__ klo,
                                                    bf16* __restrict__ vthi, bf16* __restrict__ vtlo) {
    const int K = Dsz;
    __shared__ alignas(16) bf16 ring[2][3][128 * 32];   // 48 KiB -> 3 blocks/CU
    const int t = threadIdx.x;
    const int lane = t & 63, wv = t >> 6;
    const int mw = wv >> 1, nw = wv & 1;
    int n0, m0;
    xcd_tiles(blockIdx.x, 3072 >> 7, n0, m0);
    const int r16 = lane & 15, q8 = (lane >> 4) * 8;
    const int arow = t >> 2, acol = (t & 3) * 8;

    const bf16* gAh = Ah + (size_t)(m0 + arow) * K + acol;
    const bf16* gAl = Al + (size_t)(m0 + arow) * K + acol;
    const bf16* gBh = Bh + (size_t)(n0 + arow) * K + acol;
    const size_t rK64 = (size_t)64 * K;
    const int wbase = wv * 512;
    // per-wave Bl fragment row pointers (lo weight plane stays in global/L2)
    const bf16* gBl0 = Bl + (size_t)(n0 + 64 * nw +  0 + r16) * K + q8;
    const bf16* gBl1 = Bl + (size_t)(n0 + 64 * nw + 16 + r16) * K + q8;
    const bf16* gBl2 = Bl + (size_t)(n0 + 64 * nw + 32 + r16) * K + q8;
    const bf16* gBl3 = Bl + (size_t)(n0 + 64 * nw + 48 + r16) * K + q8;

    f32x4 acc[4][4] = {};
    bf16x8 blrA[4], blrB[4];
    const int NT = K >> 5;                              // 32 (even)

#define STAGE(kt, bi) do { \
    const int _o = (kt) << 5; \
    bf16* _l = &ring[bi][0][0]; \
    gload16(gAh + _o, _l + wbase);          gload16(gAh + _o + rK64, _l + wbase + 2048); \
    gload16(gAl + _o, _l + 4096 + wbase);   gload16(gAl + _o + rK64, _l + 4096 + wbase + 2048); \
    gload16(gBh + _o, _l + 8192 + wbase);   gload16(gBh + _o + rK64, _l + 8192 + wbase + 2048); \
} while (0)

#define BLOAD(kt, DST) do { \
    const int _o = (kt) << 5; \
    DST[0] = *(const bf16x8*)(gBl0 + _o); \
    DST[1] = *(const bf16x8*)(gBl1 + _o); \
    DST[2] = *(const bf16x8*)(gBl2 + _o); \
    DST[3] = *(const bf16x8*)(gBl3 + _o); \
} while (0)

#define COMPT(bi, BLR) do { \
    CFENCE; __builtin_amdgcn_s_barrier(); CFENCE; \
    const bf16* Lb = &ring[bi][0][0]; \
    bf16x8 ah[4], al[4], bh[4]; \
    _Pragma("unroll") \
    for (int rt = 0; rt < 4; ++rt) { \
        const int ro = (64 * mw + 16 * rt + r16) * 32 + q8; \
        ah[rt] = *(const bf16x8*)(Lb + ro); \
        al[rt] = *(const bf16x8*)(Lb + 4096 + ro); \
    } \
    _Pragma("unroll") \
    for (int ct = 0; ct < 4; ++ct) { \
        const int co = (64 * nw + 16 * ct + r16) * 32 + q8; \
        bh[ct] = *(const bf16x8*)(Lb + 8192 + co); \
    } \
    asm volatile("s_waitcnt lgkmcnt(0)" ::: "memory"); \
    __builtin_amdgcn_sched_barrier(0); \
    __builtin_amdgcn_s_setprio(1); \
    _Pragma("unroll") \
    for (int rt = 0; rt < 4; ++rt) \
        _Pragma("unroll") \
        for (int ct = 0; ct < 4; ++ct) { \
            acc[rt][ct] = __builtin_amdgcn_mfma_f32_16x16x32_bf16(ah[rt], bh[ct], acc[rt][ct], 0, 0, 0); \
            acc[rt][ct] = __builtin_amdgcn_mfma_f32_16x16x32_bf16(ah[rt], BLR[ct], acc[rt][ct], 0, 0, 0); \
            acc[rt][ct] = __builtin_amdgcn_mfma_f32_16x16x32_bf16(al[rt], bh[ct], acc[rt][ct], 0, 0, 0); \
        } \
    __builtin_amdgcn_s_setprio(0); \
    CFENCE; __builtin_amdgcn_s_barrier(); CFENCE; \
} while (0)

    BLOAD(0, blrA);
    STAGE(0, 0);                        // outstanding: 10
    int kt = 0;
    for (; kt + 2 < NT; kt += 2) {
        BLOAD(kt + 1, blrB);            // +4
        STAGE(kt + 1, 1);               // +6 -> 20
        WAITV(10);                      // drain tile kt's blr+stage
        COMPT(0, blrA);
        BLOAD(kt + 2, blrA);
        STAGE(kt + 2, 0);
        WAITV(10);                      // drain tile kt+1's blr+stage
        COMPT(1, blrB);
    }
    // kt == NT-2: compute last two tiles
    BLOAD(kt + 1, blrB);
    STAGE(kt + 1, 1);
    WAITV(10);
    COMPT(0, blrA);
    WAITV(0);
    COMPT(1, blrB);

#undef STAGE
#undef BLOAD
#undef COMPT

    const int rowi = (lane >> 4) * 4;
    const int coli = lane & 15;
    if (n0 < 2048) {                 // ---- q or k: scalar hi/lo stores ----
        const float scale = (n0 < 1024) ? 0.125f : 1.0f;
        bf16* hip_ = (n0 < 1024) ? qhi : khi;
        bf16* lop_ = (n0 < 1024) ? qlo : klo;
        const int cbase = (n0 < 1024) ? n0 : (n0 - 1024);
        #pragma unroll
        for (int ct = 0; ct < 4; ++ct) {
            const int col = cbase + 64 * nw + 16 * ct + coli;
            const float bv = bias[n0 + 64 * nw + 16 * ct + coli];
            #pragma unroll
            for (int rt = 0; rt < 4; ++rt) {
                const int rowb = m0 + 64 * mw + 16 * rt + rowi;
                #pragma unroll
                for (int r = 0; r < 4; ++r) {
                    const float val = (acc[rt][ct][r] + bv) * scale;
                    const bf16 h = __float2bfloat16(val);
                    const size_t off = (size_t)(rowb + r) * Dsz + col;
                    hip_[off] = h;
                    lop_[off] = __float2bfloat16(val - __bfloat162float(h));
                }
            }
        }
    } else {                          // ---- v: transposed uint2 stores ----
        #pragma unroll
        for (int ct = 0; ct < 4; ++ct) {
            const int col = n0 + 64 * nw + 16 * ct + coli;
            const float bv = bias[col];
            const int c2 = col - 2048;          // (h*64 + d)
            #pragma unroll
            for (int rt = 0; rt < 4; ++rt) {
                const int rowb = m0 + 64 * mw + 16 * rt + rowi;
                const int b = rowb >> 10, s = rowb & 1023;
                bf16 hv[4], lv[4];
                #pragma unroll
                for (int r = 0; r < 4; ++r) {
                    const float val = acc[rt][ct][r] + bv;
                    hv[r] = __float2bfloat16(val);
                    lv[r] = __float2bfloat16(val - __bfloat162float(hv[r]));
                }
                const size_t vo = (size_t)b * (16 * 64 * 1024) + (size_t)c2 * 1024 + s;
                *(uint2*)&vthi[vo] = *(const uint2*)hv;
                *(uint2*)&vtlo[vo] = *(const uint2*)lv;
            }
        }
    }
}

// ---------------------------------------------------------------------------
// Single-pass GEMM, pipelined (2-deep ring, 32 KiB, vmcnt(4) steady),
// split-K over gridDim.z (bf16-exact A).
// ---------------------------------------------------------------------------
__global__ __launch_bounds__(256) void gemm1_pipe(const bf16* __restrict__ A,
                                                  const bf16* __restrict__ Bt,
                                                  const float* __restrict__ bias,
                                                  float* __restrict__ Cf,
                                                  int M, int N, int K) {
    __shared__ alignas(16) bf16 ring[2][2][128 * 32];   // 32 KiB
    const int t = threadIdx.x;
    const int lane = t & 63, wv = t >> 6;
    const int mw = wv >> 1, nw = wv & 1;
    int n0, m0;
    xcd_tiles(blockIdx.x, N >> 7, n0, m0);
    const int z = blockIdx.z, nz = gridDim.z;
    const int Ks = K / nz, koff = z * Ks;
    const int r16 = lane & 15, q8 = (lane >> 4) * 8;
    const int arow = t >> 2, acol = (t & 3) * 8;

    const bf16* gA = A + (size_t)(m0 + arow) * K + koff + acol;
    const bf16* gB = Bt + (size_t)(n0 + arow) * K + koff + acol;
    const size_t rK64 = (size_t)64 * K;
    const int wbase = wv * 512;

    f32x4 acc[4][4] = {};
    const int NT = Ks >> 5;

#define STAGE(kt, bi) do { \
    const int _o = (kt) << 5; \
    bf16* _l = &ring[bi][0][0]; \
    gload16(gA + _o, _l + wbase);          gload16(gA + _o + rK64, _l + wbase + 2048); \
    gload16(gB + _o, _l + 4096 + wbase);   gload16(gB + _o + rK64, _l + 4096 + wbase + 2048); \
} while (0)

#define COMPT(bi) do { \
    CFENCE; __builtin_amdgcn_s_barrier(); CFENCE; \
    const bf16* Lb = &ring[bi][0][0]; \
    bf16x8 af[4], bf_[4]; \
    _Pragma("unroll") \
    for (int rt = 0; rt < 4; ++rt) \
        af[rt] = *(const bf16x8*)(Lb + (64 * mw + 16 * rt + r16) * 32 + q8); \
    _Pragma("unroll") \
    for (int ct = 0; ct < 4; ++ct) \
        bf_[ct] = *(const bf16x8*)(Lb + 4096 + (64 * nw + 16 * ct + r16) * 32 + q8); \
    asm volatile("s_waitcnt lgkmcnt(0)" ::: "memory"); \
    __builtin_amdgcn_sched_barrier(0); \
    __builtin_amdgcn_s_setprio(1); \
    _Pragma("unroll") \
    for (int rt = 0; rt < 4; ++rt) \
        _Pragma("unroll") \
        for (int ct = 0; ct < 4; ++ct) \
            acc[rt][ct] = __builtin_amdgcn_mfma_f32_16x16x32_bf16( \
                af[rt], bf_[ct], acc[rt][ct], 0, 0, 0); \
    __builtin_amdgcn_s_setprio(0); \
    CFENCE; __builtin_amdgcn_s_barrier(); CFENCE; \
} while (0)

    STAGE(0, 0);
    int kt = 0;
    for (; kt < NT - 1; ++kt) {
        STAGE(kt + 1, (kt + 1) & 1);
        WAITV(4);
        COMPT(kt & 1);
    }
    WAITV(0);
    COMPT(kt & 1);

#undef STAGE
#undef COMPT

    float* Cz = Cf + (size_t)z * M * N;
    const int rowi = (lane >> 4) * 4;
    const int coli = lane & 15;
    #pragma unroll
    for (int ct = 0; ct < 4; ++ct) {
        const int col = n0 + 64 * nw + 16 * ct + coli;
        const float bv = (z == 0) ? bias[col] : 0.f;
        #pragma unroll
        for (int rt = 0; rt < 4; ++rt) {
            const int rowb = m0 + 64 * mw + 16 * rt + rowi;
            #pragma unroll
            for (int r = 0; r < 4; ++r)
                Cz[(size_t)(rowb + r) * N + col] = acc[rt][ct][r] + bv;
        }
    }
}

// ---------------------------------------------------------------------------
// MFMA causal flash attention v4 — barrier-free + mirror-paired strips.
// ---------------------------------------------------------------------------
__global__ __launch_bounds__(512) void attn_mfma_k(const bf16* __restrict__ qhp,
                                                   const bf16* __restrict__ qlp,
                                                   const bf16* __restrict__ khp,
                                                   const bf16* __restrict__ klp,
                                                   const bf16* __restrict__ vhp,
                                                   const bf16* __restrict__ vlp,
                                                   bf16* __restrict__ ohi,
                                                   bf16* __restrict__ olo) {
    __shared__ alignas(16) float Pf[256 * 68];              // 69632 B

    const int bh = blockIdx.x;
    const int b = bh >> 4, h = bh & 15;
    const int pr = blockIdx.y;                              // 0..3
    const int t = threadIdx.x, w = t >> 6, lane = t & 63;
    const int r16 = lane & 15, quad = lane >> 4;
    const int strip = (w < 4) ? pr : 7 - pr;
    const int qw = strip * 128 + 32 * (w & 3);              // wave's first query

    bf16x8 aQh[2][2], aQl[2][2];
    #pragma unroll
    for (int mt = 0; mt < 2; ++mt) {
        const size_t qb = (size_t)(b * Ssz + qw + 16 * mt + r16) * Dsz + h * 64 + quad * 8;
        aQh[mt][0] = *(const bf16x8*)(qhp + qb);
        aQh[mt][1] = *(const bf16x8*)(qhp + qb + 32);
        aQl[mt][0] = *(const bf16x8*)(qlp + qb);
        aQl[mt][1] = *(const bf16x8*)(qlp + qb + 32);
    }

    f32x4 aco[2][4] = {};
    float lrun[2][4] = {};
    const int ntiles = (qw + 31) / 64 + 1;

    for (int kt = 0; kt < ntiles; ++kt) {
        #pragma unroll
        for (int nt = 0; nt < 4; ++nt) {
            const size_t kb = (size_t)(b * Ssz + kt * 64 + nt * 16 + r16) * Dsz + h * 64 + quad * 8;
            const bf16x8 bKh0 = *(const bf16x8*)(khp + kb);
            const bf16x8 bKh1 = *(const bf16x8*)(khp + kb + 32);
            const bf16x8 bKl0 = *(const bf16x8*)(klp + kb);
            const bf16x8 bKl1 = *(const bf16x8*)(klp + kb + 32);
            const int key = kt * 64 + nt * 16 + r16;
            #pragma unroll
            for (int mt = 0; mt < 2; ++mt) {
                f32x4 s = {};
                s = __builtin_amdgcn_mfma_f32_16x16x32_bf16(aQh[mt][0], bKh0, s, 0, 0, 0);
                s = __builtin_amdgcn_mfma_f32_16x16x32_bf16(aQh[mt][0], bKl0, s, 0, 0, 0);
                s = __builtin_amdgcn_mfma_f32_16x16x32_bf16(aQl[mt][0], bKh0, s, 0, 0, 0);
                s = __builtin_amdgcn_mfma_f32_16x16x32_bf16(aQh[mt][1], bKh1, s, 0, 0, 0);
                s = __builtin_amdgcn_mfma_f32_16x16x32_bf16(aQh[mt][1], bKl1, s, 0, 0, 0);
                s = __builtin_amdgcn_mfma_f32_16x16x32_bf16(aQl[mt][1], bKh1, s, 0, 0, 0);
                #pragma unroll
                for (int r = 0; r < 4; ++r) {
                    const int qrow = qw + 16 * mt + quad * 4 + r;
                    const float p = (key <= qrow) ? __expf(s[r]) : 0.f;
                    lrun[mt][r] += p;
                    Pf[(32 * w + 16 * mt + quad * 4 + r) * 68 + nt * 16 + r16] = p;
                }
            }
        }

        bf16x8 aPh[2][2], aPl[2][2];
        #pragma unroll
        for (int mt = 0; mt < 2; ++mt)
            #pragma unroll
            for (int ks = 0; ks < 2; ++ks) {
                const float* pr_ = &Pf[(32 * w + 16 * mt + r16) * 68 + ks * 32 + quad * 8];
                const float4 pa = *(const float4*)pr_;
                const float4 pb = *(const float4*)(pr_ + 4);
                const float pv[8] = {pa.x, pa.y, pa.z, pa.w, pb.x, pb.y, pb.z, pb.w};
                bf16 hv[8], lv[8];
                #pragma unroll
                for (int j = 0; j < 8; ++j) {
                    hv[j] = __float2bfloat16(pv[j]);
                    lv[j] = __float2bfloat16(pv[j] - __bfloat162float(hv[j]));
                }
                aPh[mt][ks] = *(const bf16x8*)hv;
                aPl[mt][ks] = *(const bf16x8*)lv;
            }

        #pragma unroll
        for (int nt = 0; nt < 4; ++nt) {
            const size_t vb = ((size_t)bh * 64 + nt * 16 + r16) * Ssz + kt * 64 + quad * 8;
            const bf16x8 bVh0 = *(const bf16x8*)(vhp + vb);
            const bf16x8 bVh1 = *(const bf16x8*)(vhp + vb + 32);
            const bf16x8 bVl0 = *(const bf16x8*)(vlp + vb);
            const bf16x8 bVl1 = *(const bf16x8*)(vlp + vb + 32);
            #pragma unroll
            for (int mt = 0; mt < 2; ++mt) {
                aco[mt][nt] = __builtin_amdgcn_mfma_f32_16x16x32_bf16(aPh[mt][0], bVh0, aco[mt][nt], 0, 0, 0);
                aco[mt][nt] = __builtin_amdgcn_mfma_f32_16x16x32_bf16(aPh[mt][0], bVl0, aco[mt][nt], 0, 0, 0);
                aco[mt][nt] = __builtin_amdgcn_mfma_f32_16x16x32_bf16(aPl[mt][0], bVh0, aco[mt][nt], 0, 0, 0);
                aco[mt][nt] = __builtin_amdgcn_mfma_f32_16x16x32_bf16(aPh[mt][1], bVh1, aco[mt][nt], 0, 0, 0);
                aco[mt][nt] = __builtin_amdgcn_mfma_f32_16x16x32_bf16(aPh[mt][1], bVl1, aco[mt][nt], 0, 0, 0);
                aco[mt][nt] = __builtin_amdgcn_mfma_f32_16x16x32_bf16(aPl[mt][1], bVh1, aco[mt][nt], 0, 0, 0);
            }
        }
    }

    #pragma unroll
    for (int mt = 0; mt < 2; ++mt)
        #pragma unroll
        for (int r = 0; r < 4; ++r) {
            float l = lrun[mt][r];
            l += __shfl_xor(l, 1); l += __shfl_xor(l, 2);
            l += __shfl_xor(l, 4); l += __shfl_xor(l, 8);
            lrun[mt][r] = l;
        }
    #pragma unroll
    for (int mt = 0; mt < 2; ++mt)
        #pragma unroll
        for (int nt = 0; nt < 4; ++nt)
            #pragma unroll
            for (int r = 0; r < 4; ++r) {
                const size_t off = (size_t)(b * Ssz + qw + 16 * mt + quad * 4 + r) * Dsz
                                   + h * 64 + nt * 16 + r16;
                const float val = aco[mt][nt][r] / lrun[mt][r];
                const bf16 hh = __float2bfloat16(val);
                ohi[off] = hh;
                olo[off] = __float2bfloat16(val - __bfloat162float(hh));
            }
}

// ---------------------------------------------------------------------------
// LIF scan (blocks [0,64), 256 thr) MERGED with W2 transpose-cast (blocks
// [64,4160)).  Cast blocks ride along the long-running scan blocks.
// ---------------------------------------------------------------------------
__global__ __launch_bounds__(256) void scan_w2_k(const float* __restrict__ ff,
                                                 const float* __restrict__ decay,
                                                 const float* __restrict__ beta,
                                                 bf16* __restrict__ spikes,
                                                 const float* __restrict__ W2,
                                                 bf16* __restrict__ W2T) {
    __shared__ float tile[32][33];
    const int id = blockIdx.x;
    const int t = threadIdx.x;
    if (id >= 64) {
        // W2 [4096][1024] -> W2T [1024][4096] (bf16 cast)
        const int rem = id - 64;
        const int bx = (rem & 31) * 32;          // col tile over Dsz
        const int by = (rem >> 5) * 32;          // row tile over Fsz
        const int tx = t & 31, ty = t >> 5;
        #pragma unroll
        for (int i = 0; i < 32; i += 8)
            tile[ty + i][tx] = W2[(size_t)(by + ty + i) * Dsz + bx + tx];
        __syncthreads();
        #pragma unroll
        for (int i = 0; i < 32; i += 8)
            W2T[(size_t)(bx + ty + i) * Fsz + by + tx] =
                __float2bfloat16(tile[tx][ty + i]);
        return;
    }
    const int idx = id * 256 + t;
    const int b = idx >> 12;
    const int f = idx & (Fsz - 1);
    const float dec = decay[f];
    const float bet = beta[f];
    const float* src = ff + (size_t)b * Ssz * Fsz + f;
    bf16* dst = spikes + (size_t)b * Ssz * Fsz + f;
    float vm = 0.f, a = 0.f;
    float buf[64];
    #pragma unroll
    for (int u = 0; u < 64; ++u) buf[u] = src[(size_t)u * Fsz];
    for (int gg = 0; gg < 16; ++gg) {
        #pragma unroll
        for (int sub = 0; sub < 4; ++sub) {
            const int g = gg * 4 + sub;
            #pragma unroll
            for (int u = 0; u < 16; ++u) {
                vm = dec * vm + buf[sub * 16 + u];
                const float uu = vm - (1.f + a);
                const float sp = (uu > 0.f) ? 1.f : 0.f;
                vm = (uu > 0.f) ? 0.f : vm;
                a = 0.9f * a + bet * sp;
                dst[(size_t)(g * 16 + u) * Fsz] = __float2bfloat16(sp);
            }
            if (g + 4 < 64) {
                #pragma unroll
                for (int u = 0; u < 16; ++u)
                    buf[sub * 16 + u] = src[(size_t)((g + 4) * 16 + u) * Fsz];
            }
        }
    }
}

// ---------------------------------------------------------------------------
// LayerNorm 1 (blocks [0,4096)) MERGED with W1 transpose-split (blocks
// [4096,8192)).  A2 arena is free at this point (Wqkv/WoT dead).
// ---------------------------------------------------------------------------
__device__ __forceinline__ float block_sum(float val, float* ls, int t) {
    #pragma unroll
    for (int mm = 32; mm >= 1; mm >>= 1) val += __shfl_xor(val, mm);
    if ((t & 63) == 0) ls[t >> 6] = val;
    __syncthreads();
    const float r = ls[0] + ls[1] + ls[2] + ls[3];
    __syncthreads();
    return r;
}

__global__ __launch_bounds__(256) void ln1_w1_k(const float* __restrict__ x,
                                                const float* __restrict__ ap0,
                                                const float* __restrict__ ap1,
                                                const float* __restrict__ g,
                                                const float* __restrict__ bb,
                                                bf16* __restrict__ h_hi,
                                                bf16* __restrict__ h_lo,
                                                const float* __restrict__ W1,
                                                bf16* __restrict__ W1Thi,
                                                bf16* __restrict__ W1Tlo) {
    __shared__ float ls[4];
    __shared__ float tile[32][33];
    const int id = blockIdx.x;
    const int t = threadIdx.x;
    if (id >= 4096) {
        // W1 [1024][4096] -> W1T hi/lo [4096][1024]
        const int rem = id - 4096;
        const int bx = (rem & 127) * 32;         // col tile over Fsz
        const int by = (rem >> 7) * 32;          // row tile over Dsz
        const int tx = t & 31, ty = t >> 5;
        #pragma unroll
        for (int i = 0; i < 32; i += 8)
            tile[ty + i][tx] = W1[(size_t)(by + ty + i) * Fsz + bx + tx];
        __syncthreads();
        #pragma unroll
        for (int i = 0; i < 32; i += 8) {
            const float v = tile[tx][ty + i];
            const bf16 h = __float2bfloat16(v);
            const size_t o = (size_t)(bx + ty + i) * Dsz + by + tx;
            W1Thi[o] = h;
            W1Tlo[o] = __float2bfloat16(v - __bfloat162float(h));
        }
        return;
    }
    const int row = id;
    const size_t base = (size_t)row * Dsz;
    float vv[4];
    #pragma unroll
    for (int i = 0; i < 4; ++i) {
        const int c = t + i * 256;
        vv[i] = x[base + c] + (ap0[base + c] + ap1[base + c]);
    }
    float s = vv[0] + vv[1] + vv[2] + vv[3];
    s = block_sum(s, ls, t);
    const float mu = s * (1.f / 1024.f);
    float qs = 0.f;
    #pragma unroll
    for (int i = 0; i < 4; ++i) { const float d = vv[i] - mu; qs += d * d; }
    qs = block_sum(qs, ls, t);
    const float rs = rsqrtf(qs * (1.f / 1024.f) + 1e-5f);
    #pragma unroll
    for (int i = 0; i < 4; ++i) {
        const int c = t + i * 256;
        const float o = (vv[i] - mu) * rs * g[c] + bb[c];
        const bf16 hi = __float2bfloat16(o);
        h_hi[base + c] = hi;
        h_lo[base + c] = __float2bfloat16(o - __bfloat162float(hi));
    }
}

__global__ __launch_bounds__(256) void ln2_k(const bf16* __restrict__ h_hi,
                                             const bf16* __restrict__ h_lo,
                                             const float* __restrict__ fo0,
                                             const float* __restrict__ fo1,
                                             const float* __restrict__ g,
                                             const float* __restrict__ bb,
                                             float* __restrict__ out) {
    __shared__ float ls[4];
    const int row = blockIdx.x;
    const int t = threadIdx.x;
    const size_t base = (size_t)row * Dsz;
    float vv[4];
    #pragma unroll
    for (int i = 0; i < 4; ++i) {
        const int c = t + i * 256;
        const float h = __bfloat162float(h_hi[base + c]) + __bfloat162float(h_lo[base + c]);
        vv[i] = h + (fo0[base + c] + fo1[base + c]);
    }
    float s = vv[0] + vv[1] + vv[2] + vv[3];
    s = block_sum(s, ls, t);
    const float mu = s * (1.f / 1024.f);
    float qs = 0.f;
    #pragma unroll
    for (int i = 0; i < 4; ++i) { const float d = vv[i] - mu; qs += d * d; }
    qs = block_sum(qs, ls, t);
    const float rs = rsqrtf(qs * (1.f / 1024.f) + 1e-5f);
    #pragma unroll
    for (int i = 0; i < 4; ++i) {
        const int c = t + i * 256;
        out[base + c] = (vv[i] - mu) * rs * g[c] + bb[c];
    }
}

// ---------------------------------------------------------------------------
extern "C" void kernel_launch(void* const* d_in, const int* in_sizes, int n_in,
                              void* d_out, int out_size, void* d_ws, size_t ws_size,
                              hipStream_t stream) {
    const float* x    = (const float*)d_in[0];
    const float* Wq   = (const float*)d_in[1];
    const float* bq   = (const float*)d_in[2];
    const float* Wk   = (const float*)d_in[3];
    const float* bk   = (const float*)d_in[4];
    const float* Wv   = (const float*)d_in[5];
    const float* bv   = (const float*)d_in[6];
    const float* Wo   = (const float*)d_in[7];
    const float* bo   = (const float*)d_in[8];
    const float* g1   = (const float*)d_in[9];
    const float* b1   = (const float*)d_in[10];
    const float* W1   = (const float*)d_in[11];
    const float* bf1  = (const float*)d_in[12];
    const float* W2   = (const float*)d_in[13];
    const float* bf2  = (const float*)d_in[14];
    const float* g2   = (const float*)d_in[15];
    const float* b2   = (const float*)d_in[16];
    const float* dec  = (const float*)d_in[17];
    const float* beta = (const float*)d_in[18];

    const size_t BSD = (size_t)Bsz * Ssz * Dsz;
    const size_t BSF = (size_t)Bsz * Ssz * Fsz;

    // ---- workspace arenas with liveness reuse ----
    char* ws = (char*)d_ws;
    char* A3 = ws;                               // 67.1 MB
    char* A1 = A3 + BSF * 4;                     // 33.6 MB
    char* A2 = A1 + BSF * 2;                     // 16.8 MB
    char* A4 = A2 + (size_t)Dsz * Fsz * 2 * 2;   // 16.8 MB
    float* bqkv = (float*)(A4 + BSD * 4);        // 12 KB

    bf16* qhi   = (bf16*)(A3);
    bf16* qlo   = (bf16*)(A3 + BSD * 2);
    bf16* khi   = (bf16*)(A3 + BSD * 4);
    bf16* klo   = (bf16*)(A3 + BSD * 6);
    float* attnp = (float*)(A3);
    float* ffb   = (float*)(A3);
    float* ffout = (float*)(A3);

    bf16* xhi    = (bf16*)(A1);
    bf16* xlo    = (bf16*)(A1 + BSD * 2);
    bf16* athi   = (bf16*)(A1);
    bf16* atlo   = (bf16*)(A1 + BSD * 2);
    bf16* spikes = (bf16*)(A1);

    const size_t WP = (size_t)Dsz * Dsz;
    bf16* Wqkv_hi = (bf16*)(A2);
    bf16* Wqkv_lo = (bf16*)(A2 + WP * 3 * 2);
    bf16* WoThi   = (bf16*)(A2 + WP * 6 * 2);
    bf16* WoTlo   = (bf16*)(A2 + WP * 7 * 2);
    bf16* W1Thi   = (bf16*)(A2);                 // written by ln1_w1 (A2 free then)
    bf16* W1Tlo   = (bf16*)(A2 + (size_t)Dsz * Fsz * 2);
    bf16* W2T     = (bf16*)(A2);                 // written by scan_w2 (W1T dead then)

    bf16* vthi  = (bf16*)(A4);                  // [B,H,DH,S]
    bf16* vtlo  = (bf16*)(A4 + BSD * 2);
    bf16* h_hi  = (bf16*)(A4);
    bf16* h_lo  = (bf16*)(A4 + BSD * 2);

    (void)ws_size; (void)in_sizes; (void)n_in; (void)out_size;

    const int MBS = Bsz * Ssz;

    // Phase A: merged prep (4 DxD weight transpose-splits + x split + bias)
    prep_k<<<8192, 256, 0, stream>>>(x, Wq, Wk, Wv, Wo, xhi, xlo,
                                     Wqkv_hi, Wqkv_lo, WoThi, WoTlo,
                                     bq, bk, bv, bqkv);

    // Phase B: fused QKV projection (48 KiB ring, blr dbuf, single round)
    gemm3_qkv<<<dim3(24 * 32), 256, 0, stream>>>(
        xhi, xlo, Wqkv_hi, Wqkv_lo, bqkv, qhi, qlo, khi, klo, vthi, vtlo);

    // Phase C: barrier-free, mirror-paired MFMA attention
    attn_mfma_k<<<dim3(Bsz * Hsz, 4), 512, 0, stream>>>(
        qhi, qlo, khi, klo, vthi, vtlo, athi, atlo);

    // Phase D: output projection (split-K=2, pipelined) + LN1 (+W1T prep)
    gemm3_pipe<<<dim3(8 * 32, 1, 2), 256, 0, stream>>>(
        athi, atlo, WoThi, WoTlo, bo, attnp, MBS, Dsz, Dsz);
    ln1_w1_k<<<8192, 256, 0, stream>>>(x, attnp, attnp + (size_t)MBS * Dsz,
                                       g1, b1, h_hi, h_lo, W1, W1Thi, W1Tlo);

    // Phase E: FF1 — pipelined (2-deep ring, counted vmcnt, setprio)
    gemm3_pipe<<<dim3(32 * 32), 256, 0, stream>>>(
        h_hi, h_lo, W1Thi, W1Tlo, bf1, ffb, MBS, Fsz, Dsz);

    // Phase F: LIF scan (+W2T prep merged)
    scan_w2_k<<<64 + 4096, 256, 0, stream>>>(ffb, dec, beta, spikes, W2, W2T);

    // Phase G: FF2 (split-K=2, pipelined)
    gemm1_pipe<<<dim3(8 * 32, 1, 2), 256, 0, stream>>>(
        spikes, W2T, bf2, ffout, MBS, Dsz, Fsz);

    // Phase H: LN2 -> d_out
    ln2_k<<<MBS, 256, 0, stream>>>(h_hi, h_lo, ffout, ffout + (size_t)MBS * Dsz,
                                   g2, b2, (float*)d_out);
}

// Round 7
// 556.876 us; speedup vs baseline: 1.0333x; 1.0180x over previous
//
#include <hip/hip_runtime.h>
#include <hip/hip_bf16.h>
#include <stdint.h>

#define Bsz 4
#define Ssz 1024
#define Dsz 1024
#define Hsz 16
#define Fsz 4096

typedef __hip_bfloat16 bf16;
typedef __attribute__((ext_vector_type(8))) short bf16x8;
typedef __attribute__((ext_vector_type(4))) float f32x4;

typedef __attribute__((address_space(1))) const void gvoid_t;
typedef __attribute__((address_space(3))) void svoid_t;

__device__ __forceinline__ void gload16(const bf16* g, bf16* l) {
    __builtin_amdgcn_global_load_lds((gvoid_t*)g, (svoid_t*)l, 16, 0, 0);
}

#define WAITV(n) asm volatile("s_waitcnt vmcnt(" #n ")" ::: "memory")
#define CFENCE asm volatile("" ::: "memory")

// XCD-aware swizzle (kept from R11: measured neutral, harmless).
__device__ __forceinline__ void xcd_tiles(int p, int nT, int& n0, int& m0) {
    const int W8 = nT >> 3;
    const int n = (p & 7) * W8 + ((p >> 3) % W8);
    const int m = p / (8 * W8);
    n0 = n << 7;
    m0 = m << 7;
}

// ---------------------------------------------------------------------------
// Merged prep: blocks [0,4096) transpose+split the four D x D weights;
// blocks [4096,8192) split x into hi/lo planes (first 3 also copy qkv bias).
// ---------------------------------------------------------------------------
__global__ __launch_bounds__(256) void prep_k(const float* __restrict__ x,
                                              const float* __restrict__ Wq,
                                              const float* __restrict__ Wk,
                                              const float* __restrict__ Wv,
                                              const float* __restrict__ Wo,
                                              bf16* __restrict__ xhi,
                                              bf16* __restrict__ xlo,
                                              bf16* __restrict__ qkv_hi,
                                              bf16* __restrict__ qkv_lo,
                                              bf16* __restrict__ wo_hi,
                                              bf16* __restrict__ wo_lo,
                                              const float* __restrict__ bq,
                                              const float* __restrict__ bk,
                                              const float* __restrict__ bv,
                                              float* __restrict__ bqkv) {
    const int id = blockIdx.x;
    const int t = threadIdx.x;
    if (id < 4096) {
        __shared__ float tile[32][33];
        const int z = id >> 10, rem = id & 1023;
        const int bx = (rem & 31) * 32, by = (rem >> 5) * 32;
        const float* in = (z == 0) ? Wq : (z == 1) ? Wk : (z == 2) ? Wv : Wo;
        const size_t WP = (size_t)Dsz * Dsz;
        bf16* hiT = (z < 3) ? qkv_hi + (size_t)z * WP : wo_hi;
        bf16* loT = (z < 3) ? qkv_lo + (size_t)z * WP : wo_lo;
        const int tx = t & 31, ty = t >> 5;
        #pragma unroll
        for (int i = 0; i < 32; i += 8)
            tile[ty + i][tx] = in[(size_t)(by + ty + i) * Dsz + bx + tx];
        __syncthreads();
        #pragma unroll
        for (int i = 0; i < 32; i += 8) {
            const float v = tile[tx][ty + i];
            const bf16 h = __float2bfloat16(v);
            const size_t o = (size_t)(bx + ty + i) * Dsz + by + tx;
            hiT[o] = h;
            loT[o] = __float2bfloat16(v - __bfloat162float(h));
        }
    } else {
        const int sb = id - 4096;
        const int i = (sb * 256 + t) * 4;
        const float4 v = *(const float4*)(x + i);
        float vv[4] = {v.x, v.y, v.z, v.w};
        #pragma unroll
        for (int u = 0; u < 4; ++u) {
            const bf16 h = __float2bfloat16(vv[u]);
            xhi[i + u] = h;
            xlo[i + u] = __float2bfloat16(vv[u] - __bfloat162float(h));
        }
        if (sb < 3) {
            const float* bsrc = (sb == 0) ? bq : (sb == 1) ? bk : bv;
            const int j = t * 4;
            *(float4*)(bqkv + sb * 1024 + j) = *(const float4*)(bsrc + j);
        }
    }
}

// ---------------------------------------------------------------------------
// Pipelined hi/lo GEMM (T3+T4+T5, verified R2 on FF1): 2-deep LDS ring
// (64 KiB), raw s_barrier (no vmcnt(0) drain), counted s_waitcnt vmcnt(8)
// in steady state, setprio(1) around the 48-MFMA cluster.  Split-K over
// gridDim.z.  Numerics identical to the old gemm3_bt.
// ---------------------------------------------------------------------------
__global__ __launch_bounds__(256) void gemm3_pipe(const bf16* __restrict__ Ah,
                                                  const bf16* __restrict__ Al,
                                                  const bf16* __restrict__ Bh,
                                                  const bf16* __restrict__ Bl,
                                                  const float* __restrict__ bias,
                                                  float* __restrict__ Cf,
                                                  int M, int N, int K) {
    __shared__ alignas(16) bf16 ring[2][4][128 * 32];   // 64 KiB
    const int t = threadIdx.x;
    const int lane = t & 63, wv = t >> 6;
    const int mw = wv >> 1, nw = wv & 1;
    int n0, m0;
    xcd_tiles(blockIdx.x, N >> 7, n0, m0);
    const int z = blockIdx.z, nz = gridDim.z;
    const int Ks = K / nz, koff = z * Ks;
    const int r16 = lane & 15, q8 = (lane >> 4) * 8;
    const int arow = t >> 2, acol = (t & 3) * 8;

    const bf16* gAh = Ah + (size_t)(m0 + arow) * K + koff + acol;
    const bf16* gAl = Al + (size_t)(m0 + arow) * K + koff + acol;
    const bf16* gBh = Bh + (size_t)(n0 + arow) * K + koff + acol;
    const bf16* gBl = Bl + (size_t)(n0 + arow) * K + koff + acol;
    const size_t rK64 = (size_t)64 * K;
    const int wbase = wv * 512;

    f32x4 acc[4][4] = {};
    const int NT = Ks >> 5;

#define STAGE(kt, bi) do { \
    const int _o = (kt) << 5; \
    bf16* _l = &ring[bi][0][0]; \
    gload16(gAh + _o, _l + wbase);          gload16(gAh + _o + rK64, _l + wbase + 2048); \
    gload16(gAl + _o, _l + 4096 + wbase);   gload16(gAl + _o + rK64, _l + 4096 + wbase + 2048); \
    gload16(gBh + _o, _l + 8192 + wbase);   gload16(gBh + _o + rK64, _l + 8192 + wbase + 2048); \
    gload16(gBl + _o, _l + 12288 + wbase);  gload16(gBl + _o + rK64, _l + 12288 + wbase + 2048); \
} while (0)

#define COMPT(bi) do { \
    CFENCE; __builtin_amdgcn_s_barrier(); CFENCE; \
    const bf16* Lb = &ring[bi][0][0]; \
    bf16x8 ah[4], al[4], bh[4], bl[4]; \
    _Pragma("unroll") \
    for (int rt = 0; rt < 4; ++rt) { \
        const int ro = (64 * mw + 16 * rt + r16) * 32 + q8; \
        ah[rt] = *(const bf16x8*)(Lb + ro); \
        al[rt] = *(const bf16x8*)(Lb + 4096 + ro); \
    } \
    _Pragma("unroll") \
    for (int ct = 0; ct < 4; ++ct) { \
        const int co = (64 * nw + 16 * ct + r16) * 32 + q8; \
        bh[ct] = *(const bf16x8*)(Lb + 8192 + co); \
        bl[ct] = *(const bf16x8*)(Lb + 12288 + co); \
    } \
    asm volatile("s_waitcnt lgkmcnt(0)" ::: "memory"); \
    __builtin_amdgcn_sched_barrier(0); \
    __builtin_amdgcn_s_setprio(1); \
    _Pragma("unroll") \
    for (int rt = 0; rt < 4; ++rt) \
        _Pragma("unroll") \
        for (int ct = 0; ct < 4; ++ct) { \
            acc[rt][ct] = __builtin_amdgcn_mfma_f32_16x16x32_bf16(ah[rt], bh[ct], acc[rt][ct], 0, 0, 0); \
            acc[rt][ct] = __builtin_amdgcn_mfma_f32_16x16x32_bf16(ah[rt], bl[ct], acc[rt][ct], 0, 0, 0); \
            acc[rt][ct] = __builtin_amdgcn_mfma_f32_16x16x32_bf16(al[rt], bh[ct], acc[rt][ct], 0, 0, 0); \
        } \
    __builtin_amdgcn_s_setprio(0); \
    CFENCE; __builtin_amdgcn_s_barrier(); CFENCE; \
} while (0)

    STAGE(0, 0);
    int kt = 0;
    for (; kt < NT - 1; ++kt) {
        STAGE(kt + 1, (kt + 1) & 1);
        WAITV(8);                       // drain only tile kt's 8 loads
        COMPT(kt & 1);
    }
    WAITV(0);
    COMPT(kt & 1);

#undef STAGE
#undef COMPT

    float* Cz = Cf + (size_t)z * M * N;
    const int rowi = (lane >> 4) * 4;
    const int coli = lane & 15;
    #pragma unroll
    for (int ct = 0; ct < 4; ++ct) {
        const int col = n0 + 64 * nw + 16 * ct + coli;
        const float bvv = (z == 0) ? bias[col] : 0.f;
        #pragma unroll
        for (int rt = 0; rt < 4; ++rt) {
            const int rowb = m0 + 64 * mw + 16 * rt + rowi;
            #pragma unroll
            for (int r = 0; r < 4; ++r)
                Cz[(size_t)(rowb + r) * N + col] = acc[rt][ct][r] + bvv;
        }
    }
}

// ---------------------------------------------------------------------------
// QKV GEMM (N=3072) — R7: exact revert to the R3 version (measured ~105 us):
// 64 KiB 2-deep ring with all four planes in LDS, counted vmcnt(8), raw
// barriers, setprio; R3 scalar-store epilogue.  The R5/R6 3-blocks/CU
// restructures both lost more than the 1.5-round tail they recovered.
// ---------------------------------------------------------------------------
__global__ __launch_bounds__(256) void gemm3_qkv(const bf16* __restrict__ Ah,
                                                 const bf16* __restrict__ Al,
                                                 const bf16* __restrict__ Bh,
                                                 const bf16* __restrict__ Bl,
                                                 const float* __restrict__ bias,
                                                 bf16* __restrict__ qhi, bf16* __restrict__ qlo,
                                                 bf16* __restrict__ khi, bf16* __restrict__ klo,
                                                 bf16* __restrict__ vthi, bf16* __restrict__ vtlo) {
    const int K = Dsz;
    __shared__ alignas(16) bf16 ring[2][4][128 * 32];   // 64 KiB
    const int t = threadIdx.x;
    const int lane = t & 63, wv = t >> 6;
    const int mw = wv >> 1, nw = wv & 1;
    int n0, m0;
    xcd_tiles(blockIdx.x, 3072 >> 7, n0, m0);
    const int r16 = lane & 15, q8 = (lane >> 4) * 8;
    const int arow = t >> 2, acol = (t & 3) * 8;

    const bf16* gAh = Ah + (size_t)(m0 + arow) * K + acol;
    const bf16* gAl = Al + (size_t)(m0 + arow) * K + acol;
    const bf16* gBh = Bh + (size_t)(n0 + arow) * K + acol;
    const bf16* gBl = Bl + (size_t)(n0 + arow) * K + acol;
    const size_t rK64 = (size_t)64 * K;
    const int wbase = wv * 512;

    f32x4 acc[4][4] = {};
    const int NT = K >> 5;                              // 32

#define STAGE(kt, bi) do { \
    const int _o = (kt) << 5; \
    bf16* _l = &ring[bi][0][0]; \
    gload16(gAh + _o, _l + wbase);          gload16(gAh + _o + rK64, _l + wbase + 2048); \
    gload16(gAl + _o, _l + 4096 + wbase);   gload16(gAl + _o + rK64, _l + 4096 + wbase + 2048); \
    gload16(gBh + _o, _l + 8192 + wbase);   gload16(gBh + _o + rK64, _l + 8192 + wbase + 2048); \
    gload16(gBl + _o, _l + 12288 + wbase);  gload16(gBl + _o + rK64, _l + 12288 + wbase + 2048); \
} while (0)

#define COMPT(bi) do { \
    CFENCE; __builtin_amdgcn_s_barrier(); CFENCE; \
    const bf16* Lb = &ring[bi][0][0]; \
    bf16x8 ah[4], al[4], bh[4], bl[4]; \
    _Pragma("unroll") \
    for (int rt = 0; rt < 4; ++rt) { \
        const int ro = (64 * mw + 16 * rt + r16) * 32 + q8; \
        ah[rt] = *(const bf16x8*)(Lb + ro); \
        al[rt] = *(const bf16x8*)(Lb + 4096 + ro); \
    } \
    _Pragma("unroll") \
    for (int ct = 0; ct < 4; ++ct) { \
        const int co = (64 * nw + 16 * ct + r16) * 32 + q8; \
        bh[ct] = *(const bf16x8*)(Lb + 8192 + co); \
        bl[ct] = *(const bf16x8*)(Lb + 12288 + co); \
    } \
    asm volatile("s_waitcnt lgkmcnt(0)" ::: "memory"); \
    __builtin_amdgcn_sched_barrier(0); \
    __builtin_amdgcn_s_setprio(1); \
    _Pragma("unroll") \
    for (int rt = 0; rt < 4; ++rt) \
        _Pragma("unroll") \
        for (int ct = 0; ct < 4; ++ct) { \
            acc[rt][ct] = __builtin_amdgcn_mfma_f32_16x16x32_bf16(ah[rt], bh[ct], acc[rt][ct], 0, 0, 0); \
            acc[rt][ct] = __builtin_amdgcn_mfma_f32_16x16x32_bf16(ah[rt], bl[ct], acc[rt][ct], 0, 0, 0); \
            acc[rt][ct] = __builtin_amdgcn_mfma_f32_16x16x32_bf16(al[rt], bh[ct], acc[rt][ct], 0, 0, 0); \
        } \
    __builtin_amdgcn_s_setprio(0); \
    CFENCE; __builtin_amdgcn_s_barrier(); CFENCE; \
} while (0)

    STAGE(0, 0);
    int kt = 0;
    for (; kt < NT - 1; ++kt) {
        STAGE(kt + 1, (kt + 1) & 1);
        WAITV(8);
        COMPT(kt & 1);
    }
    WAITV(0);
    COMPT(kt & 1);

#undef STAGE
#undef COMPT

    const int rowi = (lane >> 4) * 4;
    const int coli = lane & 15;
    if (n0 < 2048) {                 // ---- q or k: scalar hi/lo stores ----
        const float scale = (n0 < 1024) ? 0.125f : 1.0f;
        bf16* hip_ = (n0 < 1024) ? qhi : khi;
        bf16* lop_ = (n0 < 1024) ? qlo : klo;
        const int cbase = (n0 < 1024) ? n0 : (n0 - 1024);
        #pragma unroll
        for (int ct = 0; ct < 4; ++ct) {
            const int col = cbase + 64 * nw + 16 * ct + coli;
            const float bv = bias[n0 + 64 * nw + 16 * ct + coli];
            #pragma unroll
            for (int rt = 0; rt < 4; ++rt) {
                const int rowb = m0 + 64 * mw + 16 * rt + rowi;
                #pragma unroll
                for (int r = 0; r < 4; ++r) {
                    const float val = (acc[rt][ct][r] + bv) * scale;
                    const bf16 h = __float2bfloat16(val);
                    const size_t off = (size_t)(rowb + r) * Dsz + col;
                    hip_[off] = h;
                    lop_[off] = __float2bfloat16(val - __bfloat162float(h));
                }
            }
        }
    } else {                          // ---- v: transposed uint2 stores ----
        #pragma unroll
        for (int ct = 0; ct < 4; ++ct) {
            const int col = n0 + 64 * nw + 16 * ct + coli;
            const float bv = bias[col];
            const int c2 = col - 2048;          // (h*64 + d)
            #pragma unroll
            for (int rt = 0; rt < 4; ++rt) {
                const int rowb = m0 + 64 * mw + 16 * rt + rowi;
                const int b = rowb >> 10, s = rowb & 1023;
                bf16 hv[4], lv[4];
                #pragma unroll
                for (int r = 0; r < 4; ++r) {
                    const float val = acc[rt][ct][r] + bv;
                    hv[r] = __float2bfloat16(val);
                    lv[r] = __float2bfloat16(val - __bfloat162float(hv[r]));
                }
                const size_t vo = (size_t)b * (16 * 64 * 1024) + (size_t)c2 * 1024 + s;
                *(uint2*)&vthi[vo] = *(const uint2*)hv;
                *(uint2*)&vtlo[vo] = *(const uint2*)lv;
            }
        }
    }
}

// ---------------------------------------------------------------------------
// Single-pass GEMM, pipelined (2-deep ring, 32 KiB, vmcnt(4) steady),
// split-K over gridDim.z (bf16-exact A).
// ---------------------------------------------------------------------------
__global__ __launch_bounds__(256) void gemm1_pipe(const bf16* __restrict__ A,
                                                  const bf16* __restrict__ Bt,
                                                  const float* __restrict__ bias,
                                                  float* __restrict__ Cf,
                                                  int M, int N, int K) {
    __shared__ alignas(16) bf16 ring[2][2][128 * 32];   // 32 KiB
    const int t = threadIdx.x;
    const int lane = t & 63, wv = t >> 6;
    const int mw = wv >> 1, nw = wv & 1;
    int n0, m0;
    xcd_tiles(blockIdx.x, N >> 7, n0, m0);
    const int z = blockIdx.z, nz = gridDim.z;
    const int Ks = K / nz, koff = z * Ks;
    const int r16 = lane & 15, q8 = (lane >> 4) * 8;
    const int arow = t >> 2, acol = (t & 3) * 8;

    const bf16* gA = A + (size_t)(m0 + arow) * K + koff + acol;
    const bf16* gB = Bt + (size_t)(n0 + arow) * K + koff + acol;
    const size_t rK64 = (size_t)64 * K;
    const int wbase = wv * 512;

    f32x4 acc[4][4] = {};
    const int NT = Ks >> 5;

#define STAGE(kt, bi) do { \
    const int _o = (kt) << 5; \
    bf16* _l = &ring[bi][0][0]; \
    gload16(gA + _o, _l + wbase);          gload16(gA + _o + rK64, _l + wbase + 2048); \
    gload16(gB + _o, _l + 4096 + wbase);   gload16(gB + _o + rK64, _l + 4096 + wbase + 2048); \
} while (0)

#define COMPT(bi) do { \
    CFENCE; __builtin_amdgcn_s_barrier(); CFENCE; \
    const bf16* Lb = &ring[bi][0][0]; \
    bf16x8 af[4], bf_[4]; \
    _Pragma("unroll") \
    for (int rt = 0; rt < 4; ++rt) \
        af[rt] = *(const bf16x8*)(Lb + (64 * mw + 16 * rt + r16) * 32 + q8); \
    _Pragma("unroll") \
    for (int ct = 0; ct < 4; ++ct) \
        bf_[ct] = *(const bf16x8*)(Lb + 4096 + (64 * nw + 16 * ct + r16) * 32 + q8); \
    asm volatile("s_waitcnt lgkmcnt(0)" ::: "memory"); \
    __builtin_amdgcn_sched_barrier(0); \
    __builtin_amdgcn_s_setprio(1); \
    _Pragma("unroll") \
    for (int rt = 0; rt < 4; ++rt) \
        _Pragma("unroll") \
        for (int ct = 0; ct < 4; ++ct) \
            acc[rt][ct] = __builtin_amdgcn_mfma_f32_16x16x32_bf16( \
                af[rt], bf_[ct], acc[rt][ct], 0, 0, 0); \
    __builtin_amdgcn_s_setprio(0); \
    CFENCE; __builtin_amdgcn_s_barrier(); CFENCE; \
} while (0)

    STAGE(0, 0);
    int kt = 0;
    for (; kt < NT - 1; ++kt) {
        STAGE(kt + 1, (kt + 1) & 1);
        WAITV(4);
        COMPT(kt & 1);
    }
    WAITV(0);
    COMPT(kt & 1);

#undef STAGE
#undef COMPT

    float* Cz = Cf + (size_t)z * M * N;
    const int rowi = (lane >> 4) * 4;
    const int coli = lane & 15;
    #pragma unroll
    for (int ct = 0; ct < 4; ++ct) {
        const int col = n0 + 64 * nw + 16 * ct + coli;
        const float bv = (z == 0) ? bias[col] : 0.f;
        #pragma unroll
        for (int rt = 0; rt < 4; ++rt) {
            const int rowb = m0 + 64 * mw + 16 * rt + rowi;
            #pragma unroll
            for (int r = 0; r < 4; ++r)
                Cz[(size_t)(rowb + r) * N + col] = acc[rt][ct][r] + bv;
        }
    }
}

// ---------------------------------------------------------------------------
// MFMA causal flash attention v4 — barrier-free + mirror-paired strips.
// R7: 1-D grid with XCD-coherent mapping — the 4 pr-strips of one (b,h)
// get dispatch indices {i, i+8, i+16, i+24} (same i%8 -> same XCD), so a
// head's K/V planes (512 KB) are fetched into ONE XCD L2 and reused 4x.
// ---------------------------------------------------------------------------
__global__ __launch_bounds__(512) void attn_mfma_k(const bf16* __restrict__ qhp,
                                                   const bf16* __restrict__ qlp,
                                                   const bf16* __restrict__ khp,
                                                   const bf16* __restrict__ klp,
                                                   const bf16* __restrict__ vhp,
                                                   const bf16* __restrict__ vlp,
                                                   bf16* __restrict__ ohi,
                                                   bf16* __restrict__ olo) {
    __shared__ alignas(16) float Pf[256 * 68];              // 69632 B

    const int i = blockIdx.x;                               // 0..255
    const int pr = (i >> 3) & 3;                            // 0..3
    const int bh = (i & 7) + 8 * (i >> 5);                  // 0..63
    const int b = bh >> 4, h = bh & 15;
    const int t = threadIdx.x, w = t >> 6, lane = t & 63;
    const int r16 = lane & 15, quad = lane >> 4;
    const int strip = (w < 4) ? pr : 7 - pr;
    const int qw = strip * 128 + 32 * (w & 3);              // wave's first query

    bf16x8 aQh[2][2], aQl[2][2];
    #pragma unroll
    for (int mt = 0; mt < 2; ++mt) {
        const size_t qb = (size_t)(b * Ssz + qw + 16 * mt + r16) * Dsz + h * 64 + quad * 8;
        aQh[mt][0] = *(const bf16x8*)(qhp + qb);
        aQh[mt][1] = *(const bf16x8*)(qhp + qb + 32);
        aQl[mt][0] = *(const bf16x8*)(qlp + qb);
        aQl[mt][1] = *(const bf16x8*)(qlp + qb + 32);
    }

    f32x4 aco[2][4] = {};
    float lrun[2][4] = {};
    const int ntiles = (qw + 31) / 64 + 1;

    for (int kt = 0; kt < ntiles; ++kt) {
        #pragma unroll
        for (int nt = 0; nt < 4; ++nt) {
            const size_t kb = (size_t)(b * Ssz + kt * 64 + nt * 16 + r16) * Dsz + h * 64 + quad * 8;
            const bf16x8 bKh0 = *(const bf16x8*)(khp + kb);
            const bf16x8 bKh1 = *(const bf16x8*)(khp + kb + 32);
            const bf16x8 bKl0 = *(const bf16x8*)(klp + kb);
            const bf16x8 bKl1 = *(const bf16x8*)(klp + kb + 32);
            const int key = kt * 64 + nt * 16 + r16;
            #pragma unroll
            for (int mt = 0; mt < 2; ++mt) {
                f32x4 s = {};
                s = __builtin_amdgcn_mfma_f32_16x16x32_bf16(aQh[mt][0], bKh0, s, 0, 0, 0);
                s = __builtin_amdgcn_mfma_f32_16x16x32_bf16(aQh[mt][0], bKl0, s, 0, 0, 0);
                s = __builtin_amdgcn_mfma_f32_16x16x32_bf16(aQl[mt][0], bKh0, s, 0, 0, 0);
                s = __builtin_amdgcn_mfma_f32_16x16x32_bf16(aQh[mt][1], bKh1, s, 0, 0, 0);
                s = __builtin_amdgcn_mfma_f32_16x16x32_bf16(aQh[mt][1], bKl1, s, 0, 0, 0);
                s = __builtin_amdgcn_mfma_f32_16x16x32_bf16(aQl[mt][1], bKh1, s, 0, 0, 0);
                #pragma unroll
                for (int r = 0; r < 4; ++r) {
                    const int qrow = qw + 16 * mt + quad * 4 + r;
                    const float p = (key <= qrow) ? __expf(s[r]) : 0.f;
                    lrun[mt][r] += p;
                    Pf[(32 * w + 16 * mt + quad * 4 + r) * 68 + nt * 16 + r16] = p;
                }
            }
        }

        bf16x8 aPh[2][2], aPl[2][2];
        #pragma unroll
        for (int mt = 0; mt < 2; ++mt)
            #pragma unroll
            for (int ks = 0; ks < 2; ++ks) {
                const float* pr_ = &Pf[(32 * w + 16 * mt + r16) * 68 + ks * 32 + quad * 8];
                const float4 pa = *(const float4*)pr_;
                const float4 pb = *(const float4*)(pr_ + 4);
                const float pv[8] = {pa.x, pa.y, pa.z, pa.w, pb.x, pb.y, pb.z, pb.w};
                bf16 hv[8], lv[8];
                #pragma unroll
                for (int j = 0; j < 8; ++j) {
                    hv[j] = __float2bfloat16(pv[j]);
                    lv[j] = __float2bfloat16(pv[j] - __bfloat162float(hv[j]));
                }
                aPh[mt][ks] = *(const bf16x8*)hv;
                aPl[mt][ks] = *(const bf16x8*)lv;
            }

        #pragma unroll
        for (int nt = 0; nt < 4; ++nt) {
            const size_t vb = ((size_t)bh * 64 + nt * 16 + r16) * Ssz + kt * 64 + quad * 8;
            const bf16x8 bVh0 = *(const bf16x8*)(vhp + vb);
            const bf16x8 bVh1 = *(const bf16x8*)(vhp + vb + 32);
            const bf16x8 bVl0 = *(const bf16x8*)(vlp + vb);
            const bf16x8 bVl1 = *(const bf16x8*)(vlp + vb + 32);
            #pragma unroll
            for (int mt = 0; mt < 2; ++mt) {
                aco[mt][nt] = __builtin_amdgcn_mfma_f32_16x16x32_bf16(aPh[mt][0], bVh0, aco[mt][nt], 0, 0, 0);
                aco[mt][nt] = __builtin_amdgcn_mfma_f32_16x16x32_bf16(aPh[mt][0], bVl0, aco[mt][nt], 0, 0, 0);
                aco[mt][nt] = __builtin_amdgcn_mfma_f32_16x16x32_bf16(aPl[mt][0], bVh0, aco[mt][nt], 0, 0, 0);
                aco[mt][nt] = __builtin_amdgcn_mfma_f32_16x16x32_bf16(aPh[mt][1], bVh1, aco[mt][nt], 0, 0, 0);
                aco[mt][nt] = __builtin_amdgcn_mfma_f32_16x16x32_bf16(aPh[mt][1], bVl1, aco[mt][nt], 0, 0, 0);
                aco[mt][nt] = __builtin_amdgcn_mfma_f32_16x16x32_bf16(aPl[mt][1], bVh1, aco[mt][nt], 0, 0, 0);
            }
        }
    }

    #pragma unroll
    for (int mt = 0; mt < 2; ++mt)
        #pragma unroll
        for (int r = 0; r < 4; ++r) {
            float l = lrun[mt][r];
            l += __shfl_xor(l, 1); l += __shfl_xor(l, 2);
            l += __shfl_xor(l, 4); l += __shfl_xor(l, 8);
            lrun[mt][r] = l;
        }
    #pragma unroll
    for (int mt = 0; mt < 2; ++mt)
        #pragma unroll
        for (int nt = 0; nt < 4; ++nt)
            #pragma unroll
            for (int r = 0; r < 4; ++r) {
                const size_t off = (size_t)(b * Ssz + qw + 16 * mt + quad * 4 + r) * Dsz
                                   + h * 64 + nt * 16 + r16;
                const float val = aco[mt][nt][r] / lrun[mt][r];
                const bf16 hh = __float2bfloat16(val);
                ohi[off] = hh;
                olo[off] = __float2bfloat16(val - __bfloat162float(hh));
            }
}

// ---------------------------------------------------------------------------
// LIF scan (blocks [0,64), 256 thr) MERGED with W2 transpose-cast (blocks
// [64,4160)).  Cast blocks ride along the long-running scan blocks.
// ---------------------------------------------------------------------------
__global__ __launch_bounds__(256) void scan_w2_k(const float* __restrict__ ff,
                                                 const float* __restrict__ decay,
                                                 const float* __restrict__ beta,
                                                 bf16* __restrict__ spikes,
                                                 const float* __restrict__ W2,
                                                 bf16* __restrict__ W2T) {
    __shared__ float tile[32][33];
    const int id = blockIdx.x;
    const int t = threadIdx.x;
    if (id >= 64) {
        // W2 [4096][1024] -> W2T [1024][4096] (bf16 cast)
        const int rem = id - 64;
        const int bx = (rem & 31) * 32;          // col tile over Dsz
        const int by = (rem >> 5) * 32;          // row tile over Fsz
        const int tx = t & 31, ty = t >> 5;
        #pragma unroll
        for (int i = 0; i < 32; i += 8)
            tile[ty + i][tx] = W2[(size_t)(by + ty + i) * Dsz + bx + tx];
        __syncthreads();
        #pragma unroll
        for (int i = 0; i < 32; i += 8)
            W2T[(size_t)(bx + ty + i) * Fsz + by + tx] =
                __float2bfloat16(tile[tx][ty + i]);
        return;
    }
    const int idx = id * 256 + t;
    const int b = idx >> 12;
    const int f = idx & (Fsz - 1);
    const float dec = decay[f];
    const float bet = beta[f];
    const float* src = ff + (size_t)b * Ssz * Fsz + f;
    bf16* dst = spikes + (size_t)b * Ssz * Fsz + f;
    float vm = 0.f, a = 0.f;
    float buf[64];
    #pragma unroll
    for (int u = 0; u < 64; ++u) buf[u] = src[(size_t)u * Fsz];
    for (int gg = 0; gg < 16; ++gg) {
        #pragma unroll
        for (int sub = 0; sub < 4; ++sub) {
            const int g = gg * 4 + sub;
            #pragma unroll
            for (int u = 0; u < 16; ++u) {
                vm = dec * vm + buf[sub * 16 + u];
                const float uu = vm - (1.f + a);
                const float sp = (uu > 0.f) ? 1.f : 0.f;
                vm = (uu > 0.f) ? 0.f : vm;
                a = 0.9f * a + bet * sp;
                dst[(size_t)(g * 16 + u) * Fsz] = __float2bfloat16(sp);
            }
            if (g + 4 < 64) {
                #pragma unroll
                for (int u = 0; u < 16; ++u)
                    buf[sub * 16 + u] = src[(size_t)((g + 4) * 16 + u) * Fsz];
            }
        }
    }
}

// ---------------------------------------------------------------------------
// LayerNorm 1 (blocks [0,4096)) MERGED with W1 transpose-split (blocks
// [4096,8192)).  A2 arena is free at this point (Wqkv/WoT dead).
// ---------------------------------------------------------------------------
__device__ __forceinline__ float block_sum(float val, float* ls, int t) {
    #pragma unroll
    for (int mm = 32; mm >= 1; mm >>= 1) val += __shfl_xor(val, mm);
    if ((t & 63) == 0) ls[t >> 6] = val;
    __syncthreads();
    const float r = ls[0] + ls[1] + ls[2] + ls[3];
    __syncthreads();
    return r;
}

__global__ __launch_bounds__(256) void ln1_w1_k(const float* __restrict__ x,
                                                const float* __restrict__ ap0,
                                                const float* __restrict__ ap1,
                                                const float* __restrict__ g,
                                                const float* __restrict__ bb,
                                                bf16* __restrict__ h_hi,
                                                bf16* __restrict__ h_lo,
                                                const float* __restrict__ W1,
                                                bf16* __restrict__ W1Thi,
                                                bf16* __restrict__ W1Tlo) {
    __shared__ float ls[4];
    __shared__ float tile[32][33];
    const int id = blockIdx.x;
    const int t = threadIdx.x;
    if (id >= 4096) {
        // W1 [1024][4096] -> W1T hi/lo [4096][1024]
        const int rem = id - 4096;
        const int bx = (rem & 127) * 32;         // col tile over Fsz
        const int by = (rem >> 7) * 32;          // row tile over Dsz
        const int tx = t & 31, ty = t >> 5;
        #pragma unroll
        for (int i = 0; i < 32; i += 8)
            tile[ty + i][tx] = W1[(size_t)(by + ty + i) * Fsz + bx + tx];
        __syncthreads();
        #pragma unroll
        for (int i = 0; i < 32; i += 8) {
            const float v = tile[tx][ty + i];
            const bf16 h = __float2bfloat16(v);
            const size_t o = (size_t)(bx + ty + i) * Dsz + by + tx;
            W1Thi[o] = h;
            W1Tlo[o] = __float2bfloat16(v - __bfloat162float(h));
        }
        return;
    }
    const int row = id;
    const size_t base = (size_t)row * Dsz;
    float vv[4];
    #pragma unroll
    for (int i = 0; i < 4; ++i) {
        const int c = t + i * 256;
        vv[i] = x[base + c] + (ap0[base + c] + ap1[base + c]);
    }
    float s = vv[0] + vv[1] + vv[2] + vv[3];
    s = block_sum(s, ls, t);
    const float mu = s * (1.f / 1024.f);
    float qs = 0.f;
    #pragma unroll
    for (int i = 0; i < 4; ++i) { const float d = vv[i] - mu; qs += d * d; }
    qs = block_sum(qs, ls, t);
    const float rs = rsqrtf(qs * (1.f / 1024.f) + 1e-5f);
    #pragma unroll
    for (int i = 0; i < 4; ++i) {
        const int c = t + i * 256;
        const float o = (vv[i] - mu) * rs * g[c] + bb[c];
        const bf16 hi = __float2bfloat16(o);
        h_hi[base + c] = hi;
        h_lo[base + c] = __float2bfloat16(o - __bfloat162float(hi));
    }
}

__global__ __launch_bounds__(256) void ln2_k(const bf16* __restrict__ h_hi,
                                             const bf16* __restrict__ h_lo,
                                             const float* __restrict__ fo0,
                                             const float* __restrict__ fo1,
                                             const float* __restrict__ g,
                                             const float* __restrict__ bb,
                                             float* __restrict__ out) {
    __shared__ float ls[4];
    const int row = blockIdx.x;
    const int t = threadIdx.x;
    const size_t base = (size_t)row * Dsz;
    float vv[4];
    #pragma unroll
    for (int i = 0; i < 4; ++i) {
        const int c = t + i * 256;
        const float h = __bfloat162float(h_hi[base + c]) + __bfloat162float(h_lo[base + c]);
        vv[i] = h + (fo0[base + c] + fo1[base + c]);
    }
    float s = vv[0] + vv[1] + vv[2] + vv[3];
    s = block_sum(s, ls, t);
    const float mu = s * (1.f / 1024.f);
    float qs = 0.f;
    #pragma unroll
    for (int i = 0; i < 4; ++i) { const float d = vv[i] - mu; qs += d * d; }
    qs = block_sum(qs, ls, t);
    const float rs = rsqrtf(qs * (1.f / 1024.f) + 1e-5f);
    #pragma unroll
    for (int i = 0; i < 4; ++i) {
        const int c = t + i * 256;
        out[base + c] = (vv[i] - mu) * rs * g[c] + bb[c];
    }
}

// ---------------------------------------------------------------------------
extern "C" void kernel_launch(void* const* d_in, const int* in_sizes, int n_in,
                              void* d_out, int out_size, void* d_ws, size_t ws_size,
                              hipStream_t stream) {
    const float* x    = (const float*)d_in[0];
    const float* Wq   = (const float*)d_in[1];
    const float* bq   = (const float*)d_in[2];
    const float* Wk   = (const float*)d_in[3];
    const float* bk   = (const float*)d_in[4];
    const float* Wv   = (const float*)d_in[5];
    const float* bv   = (const float*)d_in[6];
    const float* Wo   = (const float*)d_in[7];
    const float* bo   = (const float*)d_in[8];
    const float* g1   = (const float*)d_in[9];
    const float* b1   = (const float*)d_in[10];
    const float* W1   = (const float*)d_in[11];
    const float* bf1  = (const float*)d_in[12];
    const float* W2   = (const float*)d_in[13];
    const float* bf2  = (const float*)d_in[14];
    const float* g2   = (const float*)d_in[15];
    const float* b2   = (const float*)d_in[16];
    const float* dec  = (const float*)d_in[17];
    const float* beta = (const float*)d_in[18];

    const size_t BSD = (size_t)Bsz * Ssz * Dsz;
    const size_t BSF = (size_t)Bsz * Ssz * Fsz;

    // ---- workspace arenas with liveness reuse ----
    char* ws = (char*)d_ws;
    char* A3 = ws;                               // 67.1 MB
    char* A1 = A3 + BSF * 4;                     // 33.6 MB
    char* A2 = A1 + BSF * 2;                     // 16.8 MB
    char* A4 = A2 + (size_t)Dsz * Fsz * 2 * 2;   // 16.8 MB
    float* bqkv = (float*)(A4 + BSD * 4);        // 12 KB

    bf16* qhi   = (bf16*)(A3);
    bf16* qlo   = (bf16*)(A3 + BSD * 2);
    bf16* khi   = (bf16*)(A3 + BSD * 4);
    bf16* klo   = (bf16*)(A3 + BSD * 6);
    float* attnp = (float*)(A3);
    float* ffb   = (float*)(A3);
    float* ffout = (float*)(A3);

    bf16* xhi    = (bf16*)(A1);
    bf16* xlo    = (bf16*)(A1 + BSD * 2);
    bf16* athi   = (bf16*)(A1);
    bf16* atlo   = (bf16*)(A1 + BSD * 2);
    bf16* spikes = (bf16*)(A1);

    const size_t WP = (size_t)Dsz * Dsz;
    bf16* Wqkv_hi = (bf16*)(A2);
    bf16* Wqkv_lo = (bf16*)(A2 + WP * 3 * 2);
    bf16* WoThi   = (bf16*)(A2 + WP * 6 * 2);
    bf16* WoTlo   = (bf16*)(A2 + WP * 7 * 2);
    bf16* W1Thi   = (bf16*)(A2);                 // written by ln1_w1 (A2 free then)
    bf16* W1Tlo   = (bf16*)(A2 + (size_t)Dsz * Fsz * 2);
    bf16* W2T     = (bf16*)(A2);                 // written by scan_w2 (W1T dead then)

    bf16* vthi  = (bf16*)(A4);                  // [B,H,DH,S]
    bf16* vtlo  = (bf16*)(A4 + BSD * 2);
    bf16* h_hi  = (bf16*)(A4);
    bf16* h_lo  = (bf16*)(A4 + BSD * 2);

    (void)ws_size; (void)in_sizes; (void)n_in; (void)out_size;

    const int MBS = Bsz * Ssz;

    // Phase A: merged prep (4 DxD weight transpose-splits + x split + bias)
    prep_k<<<8192, 256, 0, stream>>>(x, Wq, Wk, Wv, Wo, xhi, xlo,
                                     Wqkv_hi, Wqkv_lo, WoThi, WoTlo,
                                     bq, bk, bv, bqkv);

    // Phase B: fused QKV projection (R3 64-KiB pipelined version, ~105 us)
    gemm3_qkv<<<dim3(24 * 32), 256, 0, stream>>>(
        xhi, xlo, Wqkv_hi, Wqkv_lo, bqkv, qhi, qlo, khi, klo, vthi, vtlo);

    // Phase C: attention, 1-D grid with XCD-coherent (bh,pr) mapping
    attn_mfma_k<<<dim3(256), 512, 0, stream>>>(
        qhi, qlo, khi, klo, vthi, vtlo, athi, atlo);

    // Phase D: output projection (split-K=2, pipelined) + LN1 (+W1T prep)
    gemm3_pipe<<<dim3(8 * 32, 1, 2), 256, 0, stream>>>(
        athi, atlo, WoThi, WoTlo, bo, attnp, MBS, Dsz, Dsz);
    ln1_w1_k<<<8192, 256, 0, stream>>>(x, attnp, attnp + (size_t)MBS * Dsz,
                                       g1, b1, h_hi, h_lo, W1, W1Thi, W1Tlo);

    // Phase E: FF1 — pipelined (2-deep ring, counted vmcnt, setprio)
    gemm3_pipe<<<dim3(32 * 32), 256, 0, stream>>>(
        h_hi, h_lo, W1Thi, W1Tlo, bf1, ffb, MBS, Fsz, Dsz);

    // Phase F: LIF scan (+W2T prep merged)
    scan_w2_k<<<64 + 4096, 256, 0, stream>>>(ffb, dec, beta, spikes, W2, W2T);

    // Phase G: FF2 (split-K=2, pipelined)
    gemm1_pipe<<<dim3(8 * 32, 1, 2), 256, 0, stream>>>(
        spikes, W2T, bf2, ffout, MBS, Dsz, Fsz);

    // Phase H: LN2 -> d_out
    ln2_k<<<MBS, 256, 0, stream>>>(h_hi, h_lo, ffout, ffout + (size_t)MBS * Dsz,
                                   g2, b2, (float*)d_out);
}

// Round 8
// 554.440 us; speedup vs baseline: 1.0378x; 1.0044x over previous
//
#include <hip/hip_runtime.h>
#include <hip/hip_bf16.h>
#include <stdint.h>

#define Bsz 4
#define Ssz 1024
#define Dsz 1024
#define Hsz 16
#define Fsz 4096

typedef __hip_bfloat16 bf16;
typedef __attribute__((ext_vector_type(8))) short bf16x8;
typedef __attribute__((ext_vector_type(4))) float f32x4;

typedef __attribute__((address_space(1))) const void gvoid_t;
typedef __attribute__((address_space(3))) void svoid_t;

__device__ __forceinline__ void gload16(const bf16* g, bf16* l) {
    __builtin_amdgcn_global_load_lds((gvoid_t*)g, (svoid_t*)l, 16, 0, 0);
}

#define WAITV(n) asm volatile("s_waitcnt vmcnt(" #n ")" ::: "memory")
#define CFENCE asm volatile("" ::: "memory")

// XCD-aware swizzle (kept from R11: measured neutral, harmless).
__device__ __forceinline__ void xcd_tiles(int p, int nT, int& n0, int& m0) {
    const int W8 = nT >> 3;
    const int n = (p & 7) * W8 + ((p >> 3) % W8);
    const int m = p / (8 * W8);
    n0 = n << 7;
    m0 = m << 7;
}

// ---------------------------------------------------------------------------
// T2 chunk-XOR swizzle (R8): the [128][32] bf16 tile read as ds_read_b128 at
// (row*32 + quad*8) is an 8-way bank conflict (row stride 64B -> bank base
// in {0,16}; quad constant per 16-lane group).  Fix per rule #21: LDS dest
// stays linear (global_load_lds requirement); the GLOBAL SOURCE chunk is
// pre-permuted with s(row) = (row>>1)&3, and the fragment read applies the
// same XOR.  Post-swizzle spread = 2-way (free, m136).  Write side:
// lane covers row = 16*wv + (lane>>2), so s = (t>>3)&3.  Read side:
// row = 64*mw + 16*rt + r16, so s = (r16>>1)&3.  Bit-identical numerics.
// ---------------------------------------------------------------------------

// ---------------------------------------------------------------------------
// Merged prep: blocks [0,4096) transpose+split the four D x D weights;
// blocks [4096,8192) split x into hi/lo planes (first 3 also copy qkv bias).
// ---------------------------------------------------------------------------
__global__ __launch_bounds__(256) void prep_k(const float* __restrict__ x,
                                              const float* __restrict__ Wq,
                                              const float* __restrict__ Wk,
                                              const float* __restrict__ Wv,
                                              const float* __restrict__ Wo,
                                              bf16* __restrict__ xhi,
                                              bf16* __restrict__ xlo,
                                              bf16* __restrict__ qkv_hi,
                                              bf16* __restrict__ qkv_lo,
                                              bf16* __restrict__ wo_hi,
                                              bf16* __restrict__ wo_lo,
                                              const float* __restrict__ bq,
                                              const float* __restrict__ bk,
                                              const float* __restrict__ bv,
                                              float* __restrict__ bqkv) {
    const int id = blockIdx.x;
    const int t = threadIdx.x;
    if (id < 4096) {
        __shared__ float tile[32][33];
        const int z = id >> 10, rem = id & 1023;
        const int bx = (rem & 31) * 32, by = (rem >> 5) * 32;
        const float* in = (z == 0) ? Wq : (z == 1) ? Wk : (z == 2) ? Wv : Wo;
        const size_t WP = (size_t)Dsz * Dsz;
        bf16* hiT = (z < 3) ? qkv_hi + (size_t)z * WP : wo_hi;
        bf16* loT = (z < 3) ? qkv_lo + (size_t)z * WP : wo_lo;
        const int tx = t & 31, ty = t >> 5;
        #pragma unroll
        for (int i = 0; i < 32; i += 8)
            tile[ty + i][tx] = in[(size_t)(by + ty + i) * Dsz + bx + tx];
        __syncthreads();
        #pragma unroll
        for (int i = 0; i < 32; i += 8) {
            const float v = tile[tx][ty + i];
            const bf16 h = __float2bfloat16(v);
            const size_t o = (size_t)(bx + ty + i) * Dsz + by + tx;
            hiT[o] = h;
            loT[o] = __float2bfloat16(v - __bfloat162float(h));
        }
    } else {
        const int sb = id - 4096;
        const int i = (sb * 256 + t) * 4;
        const float4 v = *(const float4*)(x + i);
        float vv[4] = {v.x, v.y, v.z, v.w};
        #pragma unroll
        for (int u = 0; u < 4; ++u) {
            const bf16 h = __float2bfloat16(vv[u]);
            xhi[i + u] = h;
            xlo[i + u] = __float2bfloat16(vv[u] - __bfloat162float(h));
        }
        if (sb < 3) {
            const float* bsrc = (sb == 0) ? bq : (sb == 1) ? bk : bv;
            const int j = t * 4;
            *(float4*)(bqkv + sb * 1024 + j) = *(const float4*)(bsrc + j);
        }
    }
}

// ---------------------------------------------------------------------------
// Pipelined hi/lo GEMM (T3+T4+T5 + R8 T2 swizzle): 2-deep LDS ring (64 KiB),
// raw s_barrier, counted vmcnt(8), setprio around the 48-MFMA cluster.
// Split-K over gridDim.z.  Numerics identical to the old gemm3_bt.
// ---------------------------------------------------------------------------
__global__ __launch_bounds__(256) void gemm3_pipe(const bf16* __restrict__ Ah,
                                                  const bf16* __restrict__ Al,
                                                  const bf16* __restrict__ Bh,
                                                  const bf16* __restrict__ Bl,
                                                  const float* __restrict__ bias,
                                                  float* __restrict__ Cf,
                                                  int M, int N, int K) {
    __shared__ alignas(16) bf16 ring[2][4][128 * 32];   // 64 KiB
    const int t = threadIdx.x;
    const int lane = t & 63, wv = t >> 6;
    const int mw = wv >> 1, nw = wv & 1;
    int n0, m0;
    xcd_tiles(blockIdx.x, N >> 7, n0, m0);
    const int z = blockIdx.z, nz = gridDim.z;
    const int Ks = K / nz, koff = z * Ks;
    const int r16 = lane & 15;
    const int cq = ((lane >> 4) ^ ((r16 >> 1) & 3)) * 8;      // swizzled read chunk
    const int arow = t >> 2;
    const int acol = ((t & 3) ^ ((t >> 3) & 3)) * 8;          // pre-swizzled source

    const bf16* gAh = Ah + (size_t)(m0 + arow) * K + koff + acol;
    const bf16* gAl = Al + (size_t)(m0 + arow) * K + koff + acol;
    const bf16* gBh = Bh + (size_t)(n0 + arow) * K + koff + acol;
    const bf16* gBl = Bl + (size_t)(n0 + arow) * K + koff + acol;
    const size_t rK64 = (size_t)64 * K;
    const int wbase = wv * 512;

    f32x4 acc[4][4] = {};
    const int NT = Ks >> 5;

#define STAGE(kt, bi) do { \
    const int _o = (kt) << 5; \
    bf16* _l = &ring[bi][0][0]; \
    gload16(gAh + _o, _l + wbase);          gload16(gAh + _o + rK64, _l + wbase + 2048); \
    gload16(gAl + _o, _l + 4096 + wbase);   gload16(gAl + _o + rK64, _l + 4096 + wbase + 2048); \
    gload16(gBh + _o, _l + 8192 + wbase);   gload16(gBh + _o + rK64, _l + 8192 + wbase + 2048); \
    gload16(gBl + _o, _l + 12288 + wbase);  gload16(gBl + _o + rK64, _l + 12288 + wbase + 2048); \
} while (0)

#define COMPT(bi) do { \
    CFENCE; __builtin_amdgcn_s_barrier(); CFENCE; \
    const bf16* Lb = &ring[bi][0][0]; \
    bf16x8 ah[4], al[4], bh[4], bl[4]; \
    _Pragma("unroll") \
    for (int rt = 0; rt < 4; ++rt) { \
        const int ro = (64 * mw + 16 * rt + r16) * 32 + cq; \
        ah[rt] = *(const bf16x8*)(Lb + ro); \
        al[rt] = *(const bf16x8*)(Lb + 4096 + ro); \
    } \
    _Pragma("unroll") \
    for (int ct = 0; ct < 4; ++ct) { \
        const int co = (64 * nw + 16 * ct + r16) * 32 + cq; \
        bh[ct] = *(const bf16x8*)(Lb + 8192 + co); \
        bl[ct] = *(const bf16x8*)(Lb + 12288 + co); \
    } \
    asm volatile("s_waitcnt lgkmcnt(0)" ::: "memory"); \
    __builtin_amdgcn_sched_barrier(0); \
    __builtin_amdgcn_s_setprio(1); \
    _Pragma("unroll") \
    for (int rt = 0; rt < 4; ++rt) \
        _Pragma("unroll") \
        for (int ct = 0; ct < 4; ++ct) { \
            acc[rt][ct] = __builtin_amdgcn_mfma_f32_16x16x32_bf16(ah[rt], bh[ct], acc[rt][ct], 0, 0, 0); \
            acc[rt][ct] = __builtin_amdgcn_mfma_f32_16x16x32_bf16(ah[rt], bl[ct], acc[rt][ct], 0, 0, 0); \
            acc[rt][ct] = __builtin_amdgcn_mfma_f32_16x16x32_bf16(al[rt], bh[ct], acc[rt][ct], 0, 0, 0); \
        } \
    __builtin_amdgcn_s_setprio(0); \
    CFENCE; __builtin_amdgcn_s_barrier(); CFENCE; \
} while (0)

    STAGE(0, 0);
    int kt = 0;
    for (; kt < NT - 1; ++kt) {
        STAGE(kt + 1, (kt + 1) & 1);
        WAITV(8);                       // drain only tile kt's 8 loads
        COMPT(kt & 1);
    }
    WAITV(0);
    COMPT(kt & 1);

#undef STAGE
#undef COMPT

    float* Cz = Cf + (size_t)z * M * N;
    const int rowi = (lane >> 4) * 4;
    const int coli = lane & 15;
    #pragma unroll
    for (int ct = 0; ct < 4; ++ct) {
        const int col = n0 + 64 * nw + 16 * ct + coli;
        const float bvv = (z == 0) ? bias[col] : 0.f;
        #pragma unroll
        for (int rt = 0; rt < 4; ++rt) {
            const int rowb = m0 + 64 * mw + 16 * rt + rowi;
            #pragma unroll
            for (int r = 0; r < 4; ++r)
                Cz[(size_t)(rowb + r) * N + col] = acc[rt][ct][r] + bvv;
        }
    }
}

// ---------------------------------------------------------------------------
// QKV GEMM (N=3072) — R3 structure (64 KiB ring, counted vmcnt, scalar
// epilogue) + R8 T2 swizzle.
// ---------------------------------------------------------------------------
__global__ __launch_bounds__(256) void gemm3_qkv(const bf16* __restrict__ Ah,
                                                 const bf16* __restrict__ Al,
                                                 const bf16* __restrict__ Bh,
                                                 const bf16* __restrict__ Bl,
                                                 const float* __restrict__ bias,
                                                 bf16* __restrict__ qhi, bf16* __restrict__ qlo,
                                                 bf16* __restrict__ khi, bf16* __restrict__ klo,
                                                 bf16* __restrict__ vthi, bf16* __restrict__ vtlo) {
    const int K = Dsz;
    __shared__ alignas(16) bf16 ring[2][4][128 * 32];   // 64 KiB
    const int t = threadIdx.x;
    const int lane = t & 63, wv = t >> 6;
    const int mw = wv >> 1, nw = wv & 1;
    int n0, m0;
    xcd_tiles(blockIdx.x, 3072 >> 7, n0, m0);
    const int r16 = lane & 15;
    const int cq = ((lane >> 4) ^ ((r16 >> 1) & 3)) * 8;
    const int arow = t >> 2;
    const int acol = ((t & 3) ^ ((t >> 3) & 3)) * 8;

    const bf16* gAh = Ah + (size_t)(m0 + arow) * K + acol;
    const bf16* gAl = Al + (size_t)(m0 + arow) * K + acol;
    const bf16* gBh = Bh + (size_t)(n0 + arow) * K + acol;
    const bf16* gBl = Bl + (size_t)(n0 + arow) * K + acol;
    const size_t rK64 = (size_t)64 * K;
    const int wbase = wv * 512;

    f32x4 acc[4][4] = {};
    const int NT = K >> 5;                              // 32

#define STAGE(kt, bi) do { \
    const int _o = (kt) << 5; \
    bf16* _l = &ring[bi][0][0]; \
    gload16(gAh + _o, _l + wbase);          gload16(gAh + _o + rK64, _l + wbase + 2048); \
    gload16(gAl + _o, _l + 4096 + wbase);   gload16(gAl + _o + rK64, _l + 4096 + wbase + 2048); \
    gload16(gBh + _o, _l + 8192 + wbase);   gload16(gBh + _o + rK64, _l + 8192 + wbase + 2048); \
    gload16(gBl + _o, _l + 12288 + wbase);  gload16(gBl + _o + rK64, _l + 12288 + wbase + 2048); \
} while (0)

#define COMPT(bi) do { \
    CFENCE; __builtin_amdgcn_s_barrier(); CFENCE; \
    const bf16* Lb = &ring[bi][0][0]; \
    bf16x8 ah[4], al[4], bh[4], bl[4]; \
    _Pragma("unroll") \
    for (int rt = 0; rt < 4; ++rt) { \
        const int ro = (64 * mw + 16 * rt + r16) * 32 + cq; \
        ah[rt] = *(const bf16x8*)(Lb + ro); \
        al[rt] = *(const bf16x8*)(Lb + 4096 + ro); \
    } \
    _Pragma("unroll") \
    for (int ct = 0; ct < 4; ++ct) { \
        const int co = (64 * nw + 16 * ct + r16) * 32 + cq; \
        bh[ct] = *(const bf16x8*)(Lb + 8192 + co); \
        bl[ct] = *(const bf16x8*)(Lb + 12288 + co); \
    } \
    asm volatile("s_waitcnt lgkmcnt(0)" ::: "memory"); \
    __builtin_amdgcn_sched_barrier(0); \
    __builtin_amdgcn_s_setprio(1); \
    _Pragma("unroll") \
    for (int rt = 0; rt < 4; ++rt) \
        _Pragma("unroll") \
        for (int ct = 0; ct < 4; ++ct) { \
            acc[rt][ct] = __builtin_amdgcn_mfma_f32_16x16x32_bf16(ah[rt], bh[ct], acc[rt][ct], 0, 0, 0); \
            acc[rt][ct] = __builtin_amdgcn_mfma_f32_16x16x32_bf16(ah[rt], bl[ct], acc[rt][ct], 0, 0, 0); \
            acc[rt][ct] = __builtin_amdgcn_mfma_f32_16x16x32_bf16(al[rt], bh[ct], acc[rt][ct], 0, 0, 0); \
        } \
    __builtin_amdgcn_s_setprio(0); \
    CFENCE; __builtin_amdgcn_s_barrier(); CFENCE; \
} while (0)

    STAGE(0, 0);
    int kt = 0;
    for (; kt < NT - 1; ++kt) {
        STAGE(kt + 1, (kt + 1) & 1);
        WAITV(8);
        COMPT(kt & 1);
    }
    WAITV(0);
    COMPT(kt & 1);

#undef STAGE
#undef COMPT

    const int rowi = (lane >> 4) * 4;
    const int coli = lane & 15;
    if (n0 < 2048) {                 // ---- q or k: scalar hi/lo stores ----
        const float scale = (n0 < 1024) ? 0.125f : 1.0f;
        bf16* hip_ = (n0 < 1024) ? qhi : khi;
        bf16* lop_ = (n0 < 1024) ? qlo : klo;
        const int cbase = (n0 < 1024) ? n0 : (n0 - 1024);
        #pragma unroll
        for (int ct = 0; ct < 4; ++ct) {
            const int col = cbase + 64 * nw + 16 * ct + coli;
            const float bv = bias[n0 + 64 * nw + 16 * ct + coli];
            #pragma unroll
            for (int rt = 0; rt < 4; ++rt) {
                const int rowb = m0 + 64 * mw + 16 * rt + rowi;
                #pragma unroll
                for (int r = 0; r < 4; ++r) {
                    const float val = (acc[rt][ct][r] + bv) * scale;
                    const bf16 h = __float2bfloat16(val);
                    const size_t off = (size_t)(rowb + r) * Dsz + col;
                    hip_[off] = h;
                    lop_[off] = __float2bfloat16(val - __bfloat162float(h));
                }
            }
        }
    } else {                          // ---- v: transposed uint2 stores ----
        #pragma unroll
        for (int ct = 0; ct < 4; ++ct) {
            const int col = n0 + 64 * nw + 16 * ct + coli;
            const float bv = bias[col];
            const int c2 = col - 2048;          // (h*64 + d)
            #pragma unroll
            for (int rt = 0; rt < 4; ++rt) {
                const int rowb = m0 + 64 * mw + 16 * rt + rowi;
                const int b = rowb >> 10, s = rowb & 1023;
                bf16 hv[4], lv[4];
                #pragma unroll
                for (int r = 0; r < 4; ++r) {
                    const float val = acc[rt][ct][r] + bv;
                    hv[r] = __float2bfloat16(val);
                    lv[r] = __float2bfloat16(val - __bfloat162float(hv[r]));
                }
                const size_t vo = (size_t)b * (16 * 64 * 1024) + (size_t)c2 * 1024 + s;
                *(uint2*)&vthi[vo] = *(const uint2*)hv;
                *(uint2*)&vtlo[vo] = *(const uint2*)lv;
            }
        }
    }
}

// ---------------------------------------------------------------------------
// Single-pass GEMM, pipelined (2-deep ring, 32 KiB, vmcnt(4) steady) + R8
// T2 swizzle.  Split-K over gridDim.z (bf16-exact A).
// ---------------------------------------------------------------------------
__global__ __launch_bounds__(256) void gemm1_pipe(const bf16* __restrict__ A,
                                                  const bf16* __restrict__ Bt,
                                                  const float* __restrict__ bias,
                                                  float* __restrict__ Cf,
                                                  int M, int N, int K) {
    __shared__ alignas(16) bf16 ring[2][2][128 * 32];   // 32 KiB
    const int t = threadIdx.x;
    const int lane = t & 63, wv = t >> 6;
    const int mw = wv >> 1, nw = wv & 1;
    int n0, m0;
    xcd_tiles(blockIdx.x, N >> 7, n0, m0);
    const int z = blockIdx.z, nz = gridDim.z;
    const int Ks = K / nz, koff = z * Ks;
    const int r16 = lane & 15;
    const int cq = ((lane >> 4) ^ ((r16 >> 1) & 3)) * 8;
    const int arow = t >> 2;
    const int acol = ((t & 3) ^ ((t >> 3) & 3)) * 8;

    const bf16* gA = A + (size_t)(m0 + arow) * K + koff + acol;
    const bf16* gB = Bt + (size_t)(n0 + arow) * K + koff + acol;
    const size_t rK64 = (size_t)64 * K;
    const int wbase = wv * 512;

    f32x4 acc[4][4] = {};
    const int NT = Ks >> 5;

#define STAGE(kt, bi) do { \
    const int _o = (kt) << 5; \
    bf16* _l = &ring[bi][0][0]; \
    gload16(gA + _o, _l + wbase);          gload16(gA + _o + rK64, _l + wbase + 2048); \
    gload16(gB + _o, _l + 4096 + wbase);   gload16(gB + _o + rK64, _l + 4096 + wbase + 2048); \
} while (0)

#define COMPT(bi) do { \
    CFENCE; __builtin_amdgcn_s_barrier(); CFENCE; \
    const bf16* Lb = &ring[bi][0][0]; \
    bf16x8 af[4], bf_[4]; \
    _Pragma("unroll") \
    for (int rt = 0; rt < 4; ++rt) \
        af[rt] = *(const bf16x8*)(Lb + (64 * mw + 16 * rt + r16) * 32 + cq); \
    _Pragma("unroll") \
    for (int ct = 0; ct < 4; ++ct) \
        bf_[ct] = *(const bf16x8*)(Lb + 4096 + (64 * nw + 16 * ct + r16) * 32 + cq); \
    asm volatile("s_waitcnt lgkmcnt(0)" ::: "memory"); \
    __builtin_amdgcn_sched_barrier(0); \
    __builtin_amdgcn_s_setprio(1); \
    _Pragma("unroll") \
    for (int rt = 0; rt < 4; ++rt) \
        _Pragma("unroll") \
        for (int ct = 0; ct < 4; ++ct) \
            acc[rt][ct] = __builtin_amdgcn_mfma_f32_16x16x32_bf16( \
                af[rt], bf_[ct], acc[rt][ct], 0, 0, 0); \
    __builtin_amdgcn_s_setprio(0); \
    CFENCE; __builtin_amdgcn_s_barrier(); CFENCE; \
} while (0)

    STAGE(0, 0);
    int kt = 0;
    for (; kt < NT - 1; ++kt) {
        STAGE(kt + 1, (kt + 1) & 1);
        WAITV(4);
        COMPT(kt & 1);
    }
    WAITV(0);
    COMPT(kt & 1);

#undef STAGE
#undef COMPT

    float* Cz = Cf + (size_t)z * M * N;
    const int rowi = (lane >> 4) * 4;
    const int coli = lane & 15;
    #pragma unroll
    for (int ct = 0; ct < 4; ++ct) {
        const int col = n0 + 64 * nw + 16 * ct + coli;
        const float bv = (z == 0) ? bias[col] : 0.f;
        #pragma unroll
        for (int rt = 0; rt < 4; ++rt) {
            const int rowb = m0 + 64 * mw + 16 * rt + rowi;
            #pragma unroll
            for (int r = 0; r < 4; ++r)
                Cz[(size_t)(rowb + r) * N + col] = acc[rt][ct][r] + bv;
        }
    }
}

// ---------------------------------------------------------------------------
// MFMA causal flash attention v4 — barrier-free + mirror-paired strips.
// R7: 1-D grid with XCD-coherent (bh,pr) mapping (neutral, kept).
// ---------------------------------------------------------------------------
__global__ __launch_bounds__(512) void attn_mfma_k(const bf16* __restrict__ qhp,
                                                   const bf16* __restrict__ qlp,
                                                   const bf16* __restrict__ khp,
                                                   const bf16* __restrict__ klp,
                                                   const bf16* __restrict__ vhp,
                                                   const bf16* __restrict__ vlp,
                                                   bf16* __restrict__ ohi,
                                                   bf16* __restrict__ olo) {
    __shared__ alignas(16) float Pf[256 * 68];              // 69632 B

    const int i = blockIdx.x;                               // 0..255
    const int pr = (i >> 3) & 3;                            // 0..3
    const int bh = (i & 7) + 8 * (i >> 5);                  // 0..63
    const int b = bh >> 4, h = bh & 15;
    const int t = threadIdx.x, w = t >> 6, lane = t & 63;
    const int r16 = lane & 15, quad = lane >> 4;
    const int strip = (w < 4) ? pr : 7 - pr;
    const int qw = strip * 128 + 32 * (w & 3);              // wave's first query

    bf16x8 aQh[2][2], aQl[2][2];
    #pragma unroll
    for (int mt = 0; mt < 2; ++mt) {
        const size_t qb = (size_t)(b * Ssz + qw + 16 * mt + r16) * Dsz + h * 64 + quad * 8;
        aQh[mt][0] = *(const bf16x8*)(qhp + qb);
        aQh[mt][1] = *(const bf16x8*)(qhp + qb + 32);
        aQl[mt][0] = *(const bf16x8*)(qlp + qb);
        aQl[mt][1] = *(const bf16x8*)(qlp + qb + 32);
    }

    f32x4 aco[2][4] = {};
    float lrun[2][4] = {};
    const int ntiles = (qw + 31) / 64 + 1;

    for (int kt = 0; kt < ntiles; ++kt) {
        #pragma unroll
        for (int nt = 0; nt < 4; ++nt) {
            const size_t kb = (size_t)(b * Ssz + kt * 64 + nt * 16 + r16) * Dsz + h * 64 + quad * 8;
            const bf16x8 bKh0 = *(const bf16x8*)(khp + kb);
            const bf16x8 bKh1 = *(const bf16x8*)(khp + kb + 32);
            const bf16x8 bKl0 = *(const bf16x8*)(klp + kb);
            const bf16x8 bKl1 = *(const bf16x8*)(klp + kb + 32);
            const int key = kt * 64 + nt * 16 + r16;
            #pragma unroll
            for (int mt = 0; mt < 2; ++mt) {
                f32x4 s = {};
                s = __builtin_amdgcn_mfma_f32_16x16x32_bf16(aQh[mt][0], bKh0, s, 0, 0, 0);
                s = __builtin_amdgcn_mfma_f32_16x16x32_bf16(aQh[mt][0], bKl0, s, 0, 0, 0);
                s = __builtin_amdgcn_mfma_f32_16x16x32_bf16(aQl[mt][0], bKh0, s, 0, 0, 0);
                s = __builtin_amdgcn_mfma_f32_16x16x32_bf16(aQh[mt][1], bKh1, s, 0, 0, 0);
                s = __builtin_amdgcn_mfma_f32_16x16x32_bf16(aQh[mt][1], bKl1, s, 0, 0, 0);
                s = __builtin_amdgcn_mfma_f32_16x16x32_bf16(aQl[mt][1], bKh1, s, 0, 0, 0);
                #pragma unroll
                for (int r = 0; r < 4; ++r) {
                    const int qrow = qw + 16 * mt + quad * 4 + r;
                    const float p = (key <= qrow) ? __expf(s[r]) : 0.f;
                    lrun[mt][r] += p;
                    Pf[(32 * w + 16 * mt + quad * 4 + r) * 68 + nt * 16 + r16] = p;
                }
            }
        }

        bf16x8 aPh[2][2], aPl[2][2];
        #pragma unroll
        for (int mt = 0; mt < 2; ++mt)
            #pragma unroll
            for (int ks = 0; ks < 2; ++ks) {
                const float* pr_ = &Pf[(32 * w + 16 * mt + r16) * 68 + ks * 32 + quad * 8];
                const float4 pa = *(const float4*)pr_;
                const float4 pb = *(const float4*)(pr_ + 4);
                const float pv[8] = {pa.x, pa.y, pa.z, pa.w, pb.x, pb.y, pb.z, pb.w};
                bf16 hv[8], lv[8];
                #pragma unroll
                for (int j = 0; j < 8; ++j) {
                    hv[j] = __float2bfloat16(pv[j]);
                    lv[j] = __float2bfloat16(pv[j] - __bfloat162float(hv[j]));
                }
                aPh[mt][ks] = *(const bf16x8*)hv;
                aPl[mt][ks] = *(const bf16x8*)lv;
            }

        #pragma unroll
        for (int nt = 0; nt < 4; ++nt) {
            const size_t vb = ((size_t)bh * 64 + nt * 16 + r16) * Ssz + kt * 64 + quad * 8;
            const bf16x8 bVh0 = *(const bf16x8*)(vhp + vb);
            const bf16x8 bVh1 = *(const bf16x8*)(vhp + vb + 32);
            const bf16x8 bVl0 = *(const bf16x8*)(vlp + vb);
            const bf16x8 bVl1 = *(const bf16x8*)(vlp + vb + 32);
            #pragma unroll
            for (int mt = 0; mt < 2; ++mt) {
                aco[mt][nt] = __builtin_amdgcn_mfma_f32_16x16x32_bf16(aPh[mt][0], bVh0, aco[mt][nt], 0, 0, 0);
                aco[mt][nt] = __builtin_amdgcn_mfma_f32_16x16x32_bf16(aPh[mt][0], bVl0, aco[mt][nt], 0, 0, 0);
                aco[mt][nt] = __builtin_amdgcn_mfma_f32_16x16x32_bf16(aPl[mt][0], bVh0, aco[mt][nt], 0, 0, 0);
                aco[mt][nt] = __builtin_amdgcn_mfma_f32_16x16x32_bf16(aPh[mt][1], bVh1, aco[mt][nt], 0, 0, 0);
                aco[mt][nt] = __builtin_amdgcn_mfma_f32_16x16x32_bf16(aPh[mt][1], bVl1, aco[mt][nt], 0, 0, 0);
                aco[mt][nt] = __builtin_amdgcn_mfma_f32_16x16x32_bf16(aPl[mt][1], bVh1, aco[mt][nt], 0, 0, 0);
            }
        }
    }

    #pragma unroll
    for (int mt = 0; mt < 2; ++mt)
        #pragma unroll
        for (int r = 0; r < 4; ++r) {
            float l = lrun[mt][r];
            l += __shfl_xor(l, 1); l += __shfl_xor(l, 2);
            l += __shfl_xor(l, 4); l += __shfl_xor(l, 8);
            lrun[mt][r] = l;
        }
    #pragma unroll
    for (int mt = 0; mt < 2; ++mt)
        #pragma unroll
        for (int nt = 0; nt < 4; ++nt)
            #pragma unroll
            for (int r = 0; r < 4; ++r) {
                const size_t off = (size_t)(b * Ssz + qw + 16 * mt + quad * 4 + r) * Dsz
                                   + h * 64 + nt * 16 + r16;
                const float val = aco[mt][nt][r] / lrun[mt][r];
                const bf16 hh = __float2bfloat16(val);
                ohi[off] = hh;
                olo[off] = __float2bfloat16(val - __bfloat162float(hh));
            }
}

// ---------------------------------------------------------------------------
// LIF scan (blocks [0,64), 256 thr) MERGED with W2 transpose-cast (blocks
// [64,4160)).  Cast blocks ride along the long-running scan blocks.
// ---------------------------------------------------------------------------
__global__ __launch_bounds__(256) void scan_w2_k(const float* __restrict__ ff,
                                                 const float* __restrict__ decay,
                                                 const float* __restrict__ beta,
                                                 bf16* __restrict__ spikes,
                                                 const float* __restrict__ W2,
                                                 bf16* __restrict__ W2T) {
    __shared__ float tile[32][33];
    const int id = blockIdx.x;
    const int t = threadIdx.x;
    if (id >= 64) {
        // W2 [4096][1024] -> W2T [1024][4096] (bf16 cast)
        const int rem = id - 64;
        const int bx = (rem & 31) * 32;          // col tile over Dsz
        const int by = (rem >> 5) * 32;          // row tile over Fsz
        const int tx = t & 31, ty = t >> 5;
        #pragma unroll
        for (int i = 0; i < 32; i += 8)
            tile[ty + i][tx] = W2[(size_t)(by + ty + i) * Dsz + bx + tx];
        __syncthreads();
        #pragma unroll
        for (int i = 0; i < 32; i += 8)
            W2T[(size_t)(bx + ty + i) * Fsz + by + tx] =
                __float2bfloat16(tile[tx][ty + i]);
        return;
    }
    const int idx = id * 256 + t;
    const int b = idx >> 12;
    const int f = idx & (Fsz - 1);
    const float dec = decay[f];
    const float bet = beta[f];
    const float* src = ff + (size_t)b * Ssz * Fsz + f;
    bf16* dst = spikes + (size_t)b * Ssz * Fsz + f;
    float vm = 0.f, a = 0.f;
    float buf[64];
    #pragma unroll
    for (int u = 0; u < 64; ++u) buf[u] = src[(size_t)u * Fsz];
    for (int gg = 0; gg < 16; ++gg) {
        #pragma unroll
        for (int sub = 0; sub < 4; ++sub) {
            const int g = gg * 4 + sub;
            #pragma unroll
            for (int u = 0; u < 16; ++u) {
                vm = dec * vm + buf[sub * 16 + u];
                const float uu = vm - (1.f + a);
                const float sp = (uu > 0.f) ? 1.f : 0.f;
                vm = (uu > 0.f) ? 0.f : vm;
                a = 0.9f * a + bet * sp;
                dst[(size_t)(g * 16 + u) * Fsz] = __float2bfloat16(sp);
            }
            if (g + 4 < 64) {
                #pragma unroll
                for (int u = 0; u < 16; ++u)
                    buf[sub * 16 + u] = src[(size_t)((g + 4) * 16 + u) * Fsz];
            }
        }
    }
}

// ---------------------------------------------------------------------------
// LayerNorm 1 (blocks [0,4096)) MERGED with W1 transpose-split (blocks
// [4096,8192)).  A2 arena is free at this point (Wqkv/WoT dead).
// ---------------------------------------------------------------------------
__device__ __forceinline__ float block_sum(float val, float* ls, int t) {
    #pragma unroll
    for (int mm = 32; mm >= 1; mm >>= 1) val += __shfl_xor(val, mm);
    if ((t & 63) == 0) ls[t >> 6] = val;
    __syncthreads();
    const float r = ls[0] + ls[1] + ls[2] + ls[3];
    __syncthreads();
    return r;
}

__global__ __launch_bounds__(256) void ln1_w1_k(const float* __restrict__ x,
                                                const float* __restrict__ ap0,
                                                const float* __restrict__ ap1,
                                                const float* __restrict__ g,
                                                const float* __restrict__ bb,
                                                bf16* __restrict__ h_hi,
                                                bf16* __restrict__ h_lo,
                                                const float* __restrict__ W1,
                                                bf16* __restrict__ W1Thi,
                                                bf16* __restrict__ W1Tlo) {
    __shared__ float ls[4];
    __shared__ float tile[32][33];
    const int id = blockIdx.x;
    const int t = threadIdx.x;
    if (id >= 4096) {
        // W1 [1024][4096] -> W1T hi/lo [4096][1024]
        const int rem = id - 4096;
        const int bx = (rem & 127) * 32;         // col tile over Fsz
        const int by = (rem >> 7) * 32;          // row tile over Dsz
        const int tx = t & 31, ty = t >> 5;
        #pragma unroll
        for (int i = 0; i < 32; i += 8)
            tile[ty + i][tx] = W1[(size_t)(by + ty + i) * Fsz + bx + tx];
        __syncthreads();
        #pragma unroll
        for (int i = 0; i < 32; i += 8) {
            const float v = tile[tx][ty + i];
            const bf16 h = __float2bfloat16(v);
            const size_t o = (size_t)(bx + ty + i) * Dsz + by + tx;
            W1Thi[o] = h;
            W1Tlo[o] = __float2bfloat16(v - __bfloat162float(h));
        }
        return;
    }
    const int row = id;
    const size_t base = (size_t)row * Dsz;
    float vv[4];
    #pragma unroll
    for (int i = 0; i < 4; ++i) {
        const int c = t + i * 256;
        vv[i] = x[base + c] + (ap0[base + c] + ap1[base + c]);
    }
    float s = vv[0] + vv[1] + vv[2] + vv[3];
    s = block_sum(s, ls, t);
    const float mu = s * (1.f / 1024.f);
    float qs = 0.f;
    #pragma unroll
    for (int i = 0; i < 4; ++i) { const float d = vv[i] - mu; qs += d * d; }
    qs = block_sum(qs, ls, t);
    const float rs = rsqrtf(qs * (1.f / 1024.f) + 1e-5f);
    #pragma unroll
    for (int i = 0; i < 4; ++i) {
        const int c = t + i * 256;
        const float o = (vv[i] - mu) * rs * g[c] + bb[c];
        const bf16 hi = __float2bfloat16(o);
        h_hi[base + c] = hi;
        h_lo[base + c] = __float2bfloat16(o - __bfloat162float(hi));
    }
}

__global__ __launch_bounds__(256) void ln2_k(const bf16* __restrict__ h_hi,
                                             const bf16* __restrict__ h_lo,
                                             const float* __restrict__ fo0,
                                             const float* __restrict__ fo1,
                                             const float* __restrict__ g,
                                             const float* __restrict__ bb,
                                             float* __restrict__ out) {
    __shared__ float ls[4];
    const int row = blockIdx.x;
    const int t = threadIdx.x;
    const size_t base = (size_t)row * Dsz;
    float vv[4];
    #pragma unroll
    for (int i = 0; i < 4; ++i) {
        const int c = t + i * 256;
        const float h = __bfloat162float(h_hi[base + c]) + __bfloat162float(h_lo[base + c]);
        vv[i] = h + (fo0[base + c] + fo1[base + c]);
    }
    float s = vv[0] + vv[1] + vv[2] + vv[3];
    s = block_sum(s, ls, t);
    const float mu = s * (1.f / 1024.f);
    float qs = 0.f;
    #pragma unroll
    for (int i = 0; i < 4; ++i) { const float d = vv[i] - mu; qs += d * d; }
    qs = block_sum(qs, ls, t);
    const float rs = rsqrtf(qs * (1.f / 1024.f) + 1e-5f);
    #pragma unroll
    for (int i = 0; i < 4; ++i) {
        const int c = t + i * 256;
        out[base + c] = (vv[i] - mu) * rs * g[c] + bb[c];
    }
}

// ---------------------------------------------------------------------------
extern "C" void kernel_launch(void* const* d_in, const int* in_sizes, int n_in,
                              void* d_out, int out_size, void* d_ws, size_t ws_size,
                              hipStream_t stream) {
    const float* x    = (const float*)d_in[0];
    const float* Wq   = (const float*)d_in[1];
    const float* bq   = (const float*)d_in[2];
    const float* Wk   = (const float*)d_in[3];
    const float* bk   = (const float*)d_in[4];
    const float* Wv   = (const float*)d_in[5];
    const float* bv   = (const float*)d_in[6];
    const float* Wo   = (const float*)d_in[7];
    const float* bo   = (const float*)d_in[8];
    const float* g1   = (const float*)d_in[9];
    const float* b1   = (const float*)d_in[10];
    const float* W1   = (const float*)d_in[11];
    const float* bf1  = (const float*)d_in[12];
    const float* W2   = (const float*)d_in[13];
    const float* bf2  = (const float*)d_in[14];
    const float* g2   = (const float*)d_in[15];
    const float* b2   = (const float*)d_in[16];
    const float* dec  = (const float*)d_in[17];
    const float* beta = (const float*)d_in[18];

    const size_t BSD = (size_t)Bsz * Ssz * Dsz;
    const size_t BSF = (size_t)Bsz * Ssz * Fsz;

    // ---- workspace arenas with liveness reuse ----
    char* ws = (char*)d_ws;
    char* A3 = ws;                               // 67.1 MB
    char* A1 = A3 + BSF * 4;                     // 33.6 MB
    char* A2 = A1 + BSF * 2;                     // 16.8 MB
    char* A4 = A2 + (size_t)Dsz * Fsz * 2 * 2;   // 16.8 MB
    float* bqkv = (float*)(A4 + BSD * 4);        // 12 KB

    bf16* qhi   = (bf16*)(A3);
    bf16* qlo   = (bf16*)(A3 + BSD * 2);
    bf16* khi   = (bf16*)(A3 + BSD * 4);
    bf16* klo   = (bf16*)(A3 + BSD * 6);
    float* attnp = (float*)(A3);
    float* ffb   = (float*)(A3);
    float* ffout = (float*)(A3);

    bf16* xhi    = (bf16*)(A1);
    bf16* xlo    = (bf16*)(A1 + BSD * 2);
    bf16* athi   = (bf16*)(A1);
    bf16* atlo   = (bf16*)(A1 + BSD * 2);
    bf16* spikes = (bf16*)(A1);

    const size_t WP = (size_t)Dsz * Dsz;
    bf16* Wqkv_hi = (bf16*)(A2);
    bf16* Wqkv_lo = (bf16*)(A2 + WP * 3 * 2);
    bf16* WoThi   = (bf16*)(A2 + WP * 6 * 2);
    bf16* WoTlo   = (bf16*)(A2 + WP * 7 * 2);
    bf16* W1Thi   = (bf16*)(A2);                 // written by ln1_w1 (A2 free then)
    bf16* W1Tlo   = (bf16*)(A2 + (size_t)Dsz * Fsz * 2);
    bf16* W2T     = (bf16*)(A2);                 // written by scan_w2 (W1T dead then)

    bf16* vthi  = (bf16*)(A4);                  // [B,H,DH,S]
    bf16* vtlo  = (bf16*)(A4 + BSD * 2);
    bf16* h_hi  = (bf16*)(A4);
    bf16* h_lo  = (bf16*)(A4 + BSD * 2);

    (void)ws_size; (void)in_sizes; (void)n_in; (void)out_size;

    const int MBS = Bsz * Ssz;

    // Phase A: merged prep (4 DxD weight transpose-splits + x split + bias)
    prep_k<<<8192, 256, 0, stream>>>(x, Wq, Wk, Wv, Wo, xhi, xlo,
                                     Wqkv_hi, Wqkv_lo, WoThi, WoTlo,
                                     bq, bk, bv, bqkv);

    // Phase B: fused QKV projection (R3 structure + T2 swizzle)
    gemm3_qkv<<<dim3(24 * 32), 256, 0, stream>>>(
        xhi, xlo, Wqkv_hi, Wqkv_lo, bqkv, qhi, qlo, khi, klo, vthi, vtlo);

    // Phase C: attention, 1-D grid with XCD-coherent (bh,pr) mapping
    attn_mfma_k<<<dim3(256), 512, 0, stream>>>(
        qhi, qlo, khi, klo, vthi, vtlo, athi, atlo);

    // Phase D: output projection (split-K=2, pipelined + swizzle) + LN1
    gemm3_pipe<<<dim3(8 * 32, 1, 2), 256, 0, stream>>>(
        athi, atlo, WoThi, WoTlo, bo, attnp, MBS, Dsz, Dsz);
    ln1_w1_k<<<8192, 256, 0, stream>>>(x, attnp, attnp + (size_t)MBS * Dsz,
                                       g1, b1, h_hi, h_lo, W1, W1Thi, W1Tlo);

    // Phase E: FF1 — pipelined + T2 swizzle
    gemm3_pipe<<<dim3(32 * 32), 256, 0, stream>>>(
        h_hi, h_lo, W1Thi, W1Tlo, bf1, ffb, MBS, Fsz, Dsz);

    // Phase F: LIF scan (+W2T prep merged)
    scan_w2_k<<<64 + 4096, 256, 0, stream>>>(ffb, dec, beta, spikes, W2, W2T);

    // Phase G: FF2 (split-K=2, pipelined + swizzle)
    gemm1_pipe<<<dim3(8 * 32, 1, 2), 256, 0, stream>>>(
        spikes, W2T, bf2, ffout, MBS, Dsz, Fsz);

    // Phase H: LN2 -> d_out
    ln2_k<<<MBS, 256, 0, stream>>>(h_hi, h_lo, ffout, ffout + (size_t)MBS * Dsz,
                                   g2, b2, (float*)d_out);
}